// Round 12
// baseline (661.533 us; speedup 1.0000x reference)
//
#include <hip/hip_runtime.h>

typedef unsigned short u16t;
typedef unsigned int   u32t;
typedef unsigned long long u64t;

#define NNODE 100000
#define DIN   256
#define HIDN  128
#define DOUTN 64
#define NNZE  1600000
#define EDIR  500000
#define EBI   1000000
#define NBLKS 391            // ceil(NNODE/256)
#define G64   1563           // ceil(NNODE/64)
#define HISTB4 2540          // ceil((NNZE+EBI)/1024)

typedef __attribute__((ext_vector_type(8))) short bf16x8;
typedef __attribute__((ext_vector_type(4))) float f32x4;
typedef __attribute__((ext_vector_type(4))) float f4v;

__device__ __forceinline__ u16t f2bf(float f){
  u32t u = __float_as_uint(f);
  u += 0x7FFFu + ((u>>16)&1u);          // round-to-nearest-even
  return (u16t)(u>>16);
}
__device__ __forceinline__ float2 up2(u32t w){
  return make_float2(__uint_as_float(w<<16), __uint_as_float(w&0xFFFF0000u));
}

// ---------------- weight prep: fragment-ready bf16 layouts ----------------
__global__ __launch_bounds__(256) void prep_kernel(const float* __restrict__ Wg,
                                                   const float* __restrict__ Wm,
                                                   const float* __restrict__ Wsg,
                                                   u16t* __restrict__ Wg_pre,
                                                   u16t* __restrict__ Wc_pre){
  int idx = blockIdx.x*256 + threadIdx.x;       // 0..65535
  int e = idx & 7, l = (idx>>3) & 63, f = (idx>>9) & 63, sel = idx>>15;
  int k_in = ((e>>2)<<4) + ((l>>4)<<2) + (e&3);
  if(sel == 0){
    int ks = f>>3, nf = f&7;
    int k = ks*32 + k_in, n = nf*16 + (l&15);
    Wg_pre[idx] = f2bf(Wg[(size_t)k*HIDN + n]);
  } else {
    int ks = f>>4, nf = f&15;
    int k = ks*32 + k_in, c = nf*16 + (l&15);
    int half = c>>7, ci = c&127;
    const float* src = (ci&1) ? Wsg : Wm;
    Wc_pre[idx - 32768] = f2bf(src[(size_t)(half*128 + k)*DOUTN + (ci>>1)]);
  }
}

// ---------------- merged histogram, 4 edges/thread (4 atomics in flight) ----------------
__global__ __launch_bounds__(256) void histAB_kernel(const int* __restrict__ gi,
                                                     const int* __restrict__ be,
                                                     u32t* __restrict__ gcnt,
                                                     u32t* __restrict__ bcnt){
  int base = blockIdx.x*1024 + threadIdx.x;
  int keys[4]; int which[4];
  #pragma unroll
  for(int q=0;q<4;q++){
    int e = base + q*256;
    which[q] = -1;
    if(e < NNZE){ which[q] = 0; keys[q] = __builtin_nontemporal_load(&gi[e]); }
    else if(e < NNZE+EBI){ which[q] = 1; keys[q] = __builtin_nontemporal_load(&be[e-NNZE]); }
  }
  #pragma unroll
  for(int q=0;q<4;q++){
    if(which[q] == 0) atomicAdd(&gcnt[keys[q]], 1u);
    else if(which[q] == 1) atomicAdd(&bcnt[keys[q]], 1u);
  }
}

// ---------------- merged hierarchical scan ----------------
__global__ __launch_bounds__(256) void scanA_kernel(const u32t* __restrict__ gcnt,
                                                    u32t* __restrict__ goffs,
                                                    u32t* __restrict__ gpart,
                                                    const u32t* __restrict__ bcnt,
                                                    u32t* __restrict__ boffs,
                                                    u32t* __restrict__ bpart){
  __shared__ u32t sh[256];
  int b = blockIdx.x;
  const u32t* cnt; u32t *offs, *part; int blk;
  if(b < NBLKS){ cnt=gcnt; offs=goffs; part=gpart; blk=b; }
  else         { cnt=bcnt; offs=boffs; part=bpart; blk=b-NBLKS; }
  int t = threadIdx.x, idx = blk*256 + t;
  u32t v = (idx < NNODE) ? cnt[idx] : 0u;
  sh[t] = v; __syncthreads();
  #pragma unroll
  for(int off=1; off<256; off<<=1){
    u32t x = (t>=off) ? sh[t-off] : 0u;
    __syncthreads();
    sh[t] += x;
    __syncthreads();
  }
  if(idx < NNODE) offs[idx] = sh[t] - v;
  if(t == 255) part[blk] = sh[255];
}
__global__ __launch_bounds__(512) void scanB_kernel(u32t* __restrict__ gpart,
                                                    u32t* __restrict__ bpart){
  __shared__ u32t sh[512];
  u32t* part = (blockIdx.x == 0) ? gpart : bpart;
  int t = threadIdx.x;
  u32t v = (t < NBLKS) ? part[t] : 0u;
  sh[t] = v; __syncthreads();
  #pragma unroll
  for(int off=1; off<512; off<<=1){
    u32t x = (t>=off) ? sh[t-off] : 0u;
    __syncthreads();
    sh[t] += x;
    __syncthreads();
  }
  if(t < NBLKS) part[t] = sh[t] - v;
  if(t == 511) part[NBLKS] = sh[511];
}
__global__ __launch_bounds__(256) void scanC_kernel(u32t* __restrict__ goffs,
                                                    u32t* __restrict__ gcur,
                                                    const u32t* __restrict__ gpart,
                                                    u32t* __restrict__ boffs,
                                                    u32t* __restrict__ bcur,
                                                    const u32t* __restrict__ bpart){
  int b = blockIdx.x;
  u32t *offs, *cur; const u32t* part; int blk;
  if(b < NBLKS){ offs=goffs; cur=gcur; part=gpart; blk=b; }
  else         { offs=boffs; cur=bcur; part=bpart; blk=b-NBLKS; }
  int idx = blk*256 + threadIdx.x;
  if(idx < NNODE){
    u32t o = offs[idx] + part[blk];
    offs[idx] = o; cur[idx] = o;
  }
  if(idx == 0) offs[NNODE] = part[NBLKS];
}

// ---------------- merged bucket fill, 4 edges/thread (4 atomic+store chains) ----------------
__global__ __launch_bounds__(256) void bucketAB_kernel(const int* __restrict__ gi,
                                                       const float* __restrict__ gv,
                                                       const int* __restrict__ be,
                                                       const float* __restrict__ bv,
                                                       u32t* __restrict__ gcur,
                                                       u64t* __restrict__ gbuck,
                                                       u32t* __restrict__ bcur,
                                                       u64t* __restrict__ bbuck){
  int base = blockIdx.x*1024 + threadIdx.x;
  int keys[4]; u32t pays[4]; float vals[4]; int which[4];
  #pragma unroll
  for(int q=0;q<4;q++){
    int e = base + q*256;
    which[q] = -1;
    if(e < NNZE){
      which[q] = 0;
      keys[q] = __builtin_nontemporal_load(&gi[e]);
      pays[q] = (u32t)__builtin_nontemporal_load(&gi[NNZE+e]);
      vals[q] = __builtin_nontemporal_load(&gv[e]);
    } else if(e < NNZE+EBI){
      int e2 = e - NNZE;
      which[q] = 1;
      keys[q] = __builtin_nontemporal_load(&be[e2]);
      pays[q] = (u32t)__builtin_nontemporal_load(&be[EBI+e2]);
      vals[q] = __builtin_nontemporal_load(&bv[e2]);
    }
  }
  u32t pos[4];
  #pragma unroll
  for(int q=0;q<4;q++){
    if(which[q] == 0)      pos[q] = atomicAdd(&gcur[keys[q]], 1u);
    else if(which[q] == 1) pos[q] = atomicAdd(&bcur[keys[q]], 1u);
  }
  #pragma unroll
  for(int q=0;q<4;q++){
    u64t ent = (u64t)pays[q] | ((u64t)__float_as_uint(vals[q])<<32);
    if(which[q] == 0)      __builtin_nontemporal_store(ent, &gbuck[pos[q]]);
    else if(which[q] == 1) __builtin_nontemporal_store(ent, &bbuck[pos[q]]);
  }
}

// ---------------- GEMM1 (MFMA): xw[N][128] = X[N][256] @ Wg, bf16 out ----------------
__global__ __launch_bounds__(256) void gemm1_kernel(const float* __restrict__ X,
                                                    const u16t* __restrict__ Wg_pre,
                                                    u16t* __restrict__ xwb){
  __shared__ __align__(16) u16t Xs[64*256];   // 32 KB, 8B-granule XOR-swizzled
  const int t = threadIdx.x, l = t & 63, w = t >> 6;
  const int row0 = blockIdx.x * 64;
  for(int i=0;i<16;i++){
    int m = w*16 + i;
    int mg = min(row0 + m, NNODE-1);
    f4v f = __builtin_nontemporal_load((const f4v*)&X[(size_t)mg*DIN + l*4]);
    u32t lo = (u32t)f2bf(f[0]) | ((u32t)f2bf(f[1])<<16);
    u32t hi = (u32t)f2bf(f[2]) | ((u32t)f2bf(f[3])<<16);
    u32t* p = (u32t*)&Xs[m*256 + ((l ^ (m&15))<<2)];
    p[0] = lo; p[1] = hi;
  }
  __syncthreads();
  f32x4 acc[8];
  #pragma unroll
  for(int nf=0;nf<8;nf++) acc[nf] = (f32x4)(0.f);
  const int lm = l & 15, l4 = l >> 4;
  const int mrow = w*16 + lm;
  #pragma unroll 1
  for(int ks=0; ks<8; ks++){
    int kg = ks*8 + l4;
    union { uint2 u2[2]; bf16x8 v; } a;
    a.u2[0] = *(const uint2*)&Xs[mrow*256 + ((kg     ^ lm)<<2)];
    a.u2[1] = *(const uint2*)&Xs[mrow*256 + (((kg+4) ^ lm)<<2)];
    #pragma unroll
    for(int nf=0;nf<8;nf++){
      union { uint4 u4; bf16x8 v; } b;
      b.u4 = *(const uint4*)&Wg_pre[(size_t)((ks*8+nf)*64 + l)*8];
      acc[nf] = __builtin_amdgcn_mfma_f32_16x16x32_bf16(a.v, b.v, acc[nf], 0, 0, 0);
    }
  }
  #pragma unroll
  for(int r=0;r<4;r++){
    int gr = row0 + w*16 + l4*4 + r;
    if(gr < NNODE){
      #pragma unroll
      for(int nf=0;nf<8;nf++)
        xwb[(size_t)gr*HIDN + nf*16 + lm] = f2bf(acc[nf][r]);
    }
  }
}

// ---------------- GCN gather-reduce (4x unrolled gathers) ----------------
__global__ __launch_bounds__(256) void gcn_gather_kernel(const u16t* __restrict__ xwb,
                                                         const u64t* __restrict__ bucket,
                                                         const u32t* __restrict__ offs,
                                                         u32t* __restrict__ hiddenw){
  int n = blockIdx.x*4 + (threadIdx.x>>6);
  if(n >= NNODE) return;
  int l = threadIdx.x & 63;
  u32t start = offs[n], end = offs[n+1];
  const u32t* xww = (const u32t*)xwb;
  float acc0 = 0.f, acc1 = 0.f;
  for(u32t b = start; b < end; b += 64){
    int nb = min(64, (int)(end - b));
    uint2 ent = make_uint2(0u, 0u);               // lanes >= nb: s=0, v=0 (harmless)
    if(l < nb){
      u64t ev = __builtin_nontemporal_load(&bucket[b + l]);
      ent = make_uint2((u32t)ev, (u32t)(ev>>32));
    }
    int nbr = (nb + 3) & ~3;
    for(int j=0;j<nbr;j+=4){
      float2 xs[4]; float vs[4];
      #pragma unroll
      for(int q=0;q<4;q++){
        u32t s = __shfl(ent.x, j+q);
        vs[q]  = __uint_as_float(__shfl((int)ent.y, j+q));
        xs[q]  = up2(xww[(size_t)s*64 + l]);
      }
      #pragma unroll
      for(int q=0;q<4;q++){
        acc0 += vs[q]*xs[q].x;
        acc1 += vs[q]*xs[q].y;
      }
    }
  }
  hiddenw[(size_t)n*64 + l] = (u32t)f2bf(acc0) | ((u32t)f2bf(acc1)<<16);
}

// ---------------- GEMM2 (MFMA): SRCw (in-place over hiddenw) + DSTw ----------------
__global__ __launch_bounds__(256) void gemm2_kernel(u32t* __restrict__ hiddenw,
                                                    const u16t* __restrict__ Wc_pre,
                                                    u16t* __restrict__ DSTw){
  __shared__ __align__(16) u16t Hs[64*128];   // 16 KB
  const int t = threadIdx.x, l = t & 63, w = t >> 6;
  const int row0 = blockIdx.x * 64;
  for(int i=0;i<16;i++){
    int m = w*16 + i;
    int mg = min(row0 + m, NNODE-1);
    u32t v = hiddenw[(size_t)mg*64 + l];
    *(u32t*)&Hs[m*128 + (((l>>1) ^ (m&15))<<2) + ((l&1)<<1)] = v;
  }
  __syncthreads();
  f32x4 acc[16];
  #pragma unroll
  for(int nf=0;nf<16;nf++) acc[nf] = (f32x4)(0.f);
  const int lm = l & 15, l4 = l >> 4;
  const int mrow = w*16 + lm;
  #pragma unroll 1
  for(int ks=0; ks<4; ks++){
    int kg = ks*8 + l4;
    union { uint2 u2[2]; bf16x8 v; } a;
    a.u2[0] = *(const uint2*)&Hs[mrow*128 + ((kg     ^ lm)<<2)];
    a.u2[1] = *(const uint2*)&Hs[mrow*128 + (((kg+4) ^ lm)<<2)];
    #pragma unroll
    for(int nf=0;nf<16;nf++){
      union { uint4 u4; bf16x8 v; } b;
      b.u4 = *(const uint4*)&Wc_pre[(size_t)((ks*16+nf)*64 + l)*8];
      acc[nf] = __builtin_amdgcn_mfma_f32_16x16x32_bf16(a.v, b.v, acc[nf], 0, 0, 0);
    }
  }
  u16t* SRCw = (u16t*)hiddenw;   // in-place: this block's rows were staged above
  #pragma unroll
  for(int r=0;r<4;r++){
    int gr = row0 + w*16 + l4*4 + r;
    if(gr < NNODE){
      #pragma unroll
      for(int nf=0;nf<8;nf++)
        SRCw[(size_t)gr*HIDN + nf*16 + lm] = f2bf(acc[nf][r]);
      #pragma unroll
      for(int nf=8;nf<16;nf++)
        DSTw[(size_t)gr*HIDN + (nf-8)*16 + lm] = f2bf(acc[nf][r]);
    }
  }
}

// ---------------- directed-edge heads: 4 edges per wave (16 gathers in flight) ----------------
__global__ __launch_bounds__(256) void edge_kernel(const u16t* __restrict__ SRCb,
                                                   const u16t* __restrict__ DSTb,
                                                   const int*  __restrict__ ed,
                                                   const float* __restrict__ nin,
                                                   const float* __restrict__ nout,
                                                   float* __restrict__ ein,
                                                   float* __restrict__ eout){
  const int e0 = (blockIdx.x*4 + (threadIdx.x>>6))*4;
  const int l = threadIdx.x & 63;
  const u32t* Sw = (const u32t*)SRCb;
  const u32t* Dw = (const u32t*)DSTb;
  int s[4], d[4];
  #pragma unroll
  for(int q=0;q<4;q++){ s[q] = ed[e0+q]; d[q] = ed[EDIR+e0+q]; }
  float2 Ss[4], Ds[4], Sd[4], Dd[4];
  float ni[4], no[4];
  #pragma unroll
  for(int q=0;q<4;q++){
    Ss[q] = up2(Sw[(size_t)s[q]*64 + l]);
    Ds[q] = up2(Dw[(size_t)s[q]*64 + l]);
    Sd[q] = up2(Sw[(size_t)d[q]*64 + l]);
    Dd[q] = up2(Dw[(size_t)d[q]*64 + l]);
    ni[q] = __builtin_nontemporal_load(&nin[(size_t)(e0+q)*DOUTN + l]);
    no[q] = __builtin_nontemporal_load(&nout[(size_t)(e0+q)*DOUTN + l]);
  }
  #pragma unroll
  for(int q=0;q<4;q++){
    size_t o = (size_t)(e0+q)*DOUTN + l;
    float miu_in  = Ss[q].x + Dd[q].x, ls_in  = Ss[q].y + Dd[q].y;
    float miu_out = Sd[q].x + Ds[q].x, ls_out = Sd[q].y + Ds[q].y;
    __builtin_nontemporal_store(ni[q] * __expf(ls_in)  + miu_in,  &ein[o]);
    __builtin_nontemporal_store(no[q] * __expf(ls_out) + miu_out, &eout[o]);
  }
}

// ---------------- bi gather-reduce + finalize (4x unrolled gathers) ----------------
__global__ __launch_bounds__(256) void bi_gather_kernel(const u16t* __restrict__ SRCb,
                                                        const u16t* __restrict__ DSTb,
                                                        const u64t* __restrict__ bbuck,
                                                        const u32t* __restrict__ boffs,
                                                        const float* __restrict__ nn,
                                                        float* __restrict__ outp){
  int n = blockIdx.x*4 + (threadIdx.x>>6);
  if(n >= NNODE) return;
  int l = threadIdx.x & 63;
  const u32t* Sw = (const u32t*)SRCb;
  const u32t* Dw = (const u32t*)DSTb;
  float2 S = up2(Sw[(size_t)n*64 + l]);
  u32t start = boffs[n], end = boffs[n+1];
  float nmiu = 0.f, nvar = 0.f;
  for(u32t b = start; b < end; b += 64){
    int nb = min(64, (int)(end - b));
    uint2 ent = make_uint2(0u, 0u);               // lanes >= nb: v=0 (harmless)
    if(l < nb){
      u64t ev = __builtin_nontemporal_load(&bbuck[b + l]);
      ent = make_uint2((u32t)ev, (u32t)(ev>>32));
    }
    int nbr = (nb + 3) & ~3;
    for(int j=0;j<nbr;j+=4){
      float2 Dq[4]; float vs[4];
      #pragma unroll
      for(int q=0;q<4;q++){
        u32t b1 = __shfl(ent.x, j+q);
        vs[q]   = __uint_as_float(__shfl((int)ent.y, j+q));
        Dq[q]   = up2(Dw[(size_t)b1*64 + l]);
      }
      #pragma unroll
      for(int q=0;q<4;q++){
        nmiu += vs[q]*(S.x + Dq[q].x);
        nvar += vs[q]*vs[q]*__expf(S.y + Dq[q].y);
      }
    }
  }
  size_t o = (size_t)n*DOUTN + l;
  float nd = __builtin_nontemporal_load(&nn[o]);
  __builtin_nontemporal_store(nd*sqrtf(nvar) + nmiu, &outp[o]);  // exp(0.5*log v)==sqrt(v)
}

extern "C" void kernel_launch(void* const* d_in, const int* in_sizes, int n_in,
                              void* d_out, int out_size, void* d_ws, size_t ws_size,
                              hipStream_t stream){
  const float* X    = (const float*)d_in[0];
  const float* Wg   = (const float*)d_in[1];
  const float* Wm   = (const float*)d_in[2];
  const float* Wsg  = (const float*)d_in[3];
  const float* gv   = (const float*)d_in[4];
  const float* bv   = (const float*)d_in[5];
  const float* nin  = (const float*)d_in[6];
  const float* nout = (const float*)d_in[7];
  const float* nnod = (const float*)d_in[8];
  const int*  gi   = (const int*)d_in[9];
  const int*  ed   = (const int*)d_in[10];
  const int*  be   = (const int*)d_in[11];

  // workspace (76.8 MB):
  //  [0,12.8M)        gbuck u64            -> phase2: DSTw bf16 [0,25.6M)
  //  [12.8M,38.4M)    xwb bf16             -> (tail of DSTw)
  //  [38.4M,40.0M)    metadata: goffs | gcur | bcur | gpart | bpart | boffs
  //  [40.0M,48.0M)    bbuck u64 (lives until bi_gather)
  //  [51.2M,76.8M)    hiddenw u32-packed bf16 -> in-place SRCw bf16 after gemm2
  char* ws = (char*)d_ws;
  u64t*  gbuck   = (u64t*)ws;
  u16t*  xwb     = (u16t*)(ws + 12800000);
  u32t*  goffs   = (u32t*)(ws + 38400000);
  u32t*  gcur    = (u32t*)(ws + 38800008);
  u32t*  bcur    = (u32t*)(ws + 39200008);
  u32t*  gpart   = (u32t*)(ws + 39600008);
  u32t*  bpart   = (u32t*)(ws + 39601584);
  u32t*  boffs   = (u32t*)(ws + 39603160);
  u64t*  bbuck   = (u64t*)(ws + 40003168);
  u32t*  hiddenw = (u32t*)(ws + 51200000);
  u16t*  SRCw    = (u16t*)hiddenw;
  u16t*  DSTw    = (u16t*)ws;

  float* out  = (float*)d_out;
  float* ein  = out + (size_t)NNODE*DOUTN;
  float* eout = ein + (size_t)EDIR*DOUTN;
  // weight-prep arrays in tail of d_out's node region; dead before bi_gather overwrites
  u16t* Wg_pre = (u16t*)((char*)d_out + 25600000 - 131072);
  u16t* Wc_pre = Wg_pre + 32768;

  (void)hipMemsetAsync(gcur, 0, 800000, stream);                // gcur + bcur
  histAB_kernel   <<<HISTB4,  256, 0, stream>>>(gi, be, gcur, bcur);
  scanA_kernel    <<<2*NBLKS, 256, 0, stream>>>(gcur, goffs, gpart, bcur, boffs, bpart);
  scanB_kernel    <<<2,       512, 0, stream>>>(gpart, bpart);
  scanC_kernel    <<<2*NBLKS, 256, 0, stream>>>(goffs, gcur, gpart, boffs, bcur, bpart);
  bucketAB_kernel <<<HISTB4,  256, 0, stream>>>(gi, gv, be, bv, gcur, gbuck, bcur, bbuck);
  prep_kernel     <<<256,     256, 0, stream>>>(Wg, Wm, Wsg, Wg_pre, Wc_pre);
  gemm1_kernel    <<<G64,     256, 0, stream>>>(X, Wg_pre, xwb);
  gcn_gather_kernel<<<NNODE/4,256, 0, stream>>>(xwb, gbuck, goffs, hiddenw);
  gemm2_kernel    <<<G64,     256, 0, stream>>>(hiddenw, Wc_pre, DSTw);
  edge_kernel     <<<EDIR/16, 256, 0, stream>>>(SRCw, DSTw, ed, nin, nout, ein, eout);
  bi_gather_kernel<<<NNODE/4, 256, 0, stream>>>(SRCw, DSTw, bbuck, boffs, nnod, out);
}

// Round 13
// 483.987 us; speedup vs baseline: 1.3668x; 1.3668x over previous
//
#include <hip/hip_runtime.h>

typedef unsigned short u16t;
typedef unsigned int   u32t;
typedef unsigned long long u64t;

#define NNODE 100000
#define DIN   256
#define HIDN  128
#define DOUTN 64
#define NNZE  1600000
#define EDIR  500000
#define EBI   1000000
#define G64   1563           // ceil(NNODE/64)
#define NBIN  782            // ceil(NNODE/128), bin = key>>7
#define CH3   4096           // edges per partition block
#define K3G   391            // ceil(NNZE/CH3)
#define K3B   245            // ceil(EBI/CH3)
#define CAPG  2432           // gcn entries per bin cap (mean 2048, sd 45 -> 8.5 sigma)
#define CAPB  1536           // bi entries per bin cap (mean 1280, sd 34 -> 7.5 sigma)

typedef __attribute__((ext_vector_type(8))) short bf16x8;
typedef __attribute__((ext_vector_type(4))) float f32x4;
typedef __attribute__((ext_vector_type(4))) float f4v;

__device__ __forceinline__ u16t f2bf(float f){
  u32t u = __float_as_uint(f);
  u += 0x7FFFu + ((u>>16)&1u);          // round-to-nearest-even
  return (u16t)(u>>16);
}
__device__ __forceinline__ float2 up2(u32t w){
  return make_float2(__uint_as_float(w<<16), __uint_as_float(w&0xFFFF0000u));
}

// ---------------- weight prep: fragment-ready bf16 layouts ----------------
__global__ __launch_bounds__(256) void prep_kernel(const float* __restrict__ Wg,
                                                   const float* __restrict__ Wm,
                                                   const float* __restrict__ Wsg,
                                                   u16t* __restrict__ Wg_pre,
                                                   u16t* __restrict__ Wc_pre){
  int idx = blockIdx.x*256 + threadIdx.x;       // 0..65535
  int e = idx & 7, l = (idx>>3) & 63, f = (idx>>9) & 63, sel = idx>>15;
  int k_in = ((e>>2)<<4) + ((l>>4)<<2) + (e&3);
  if(sel == 0){
    int ks = f>>3, nf = f&7;
    int k = ks*32 + k_in, n = nf*16 + (l&15);
    Wg_pre[idx] = f2bf(Wg[(size_t)k*HIDN + n]);
  } else {
    int ks = f>>4, nf = f&15;
    int k = ks*32 + k_in, c = nf*16 + (l&15);
    int half = c>>7, ci = c&127;
    const float* src = (ci&1) ? Wsg : Wm;
    Wc_pre[idx - 32768] = f2bf(src[(size_t)(half*128 + k)*DOUTN + (ci>>1)]);
  }
}

// ---------------- coarse histogram over 782 bins, both streams ----------------
__global__ __launch_bounds__(256) void coarse_hist_kernel(const int* __restrict__ gi,
                                                          const int* __restrict__ be,
                                                          u32t* __restrict__ gcnt_c,
                                                          u32t* __restrict__ bcnt_c){
  __shared__ u32t h[1024];
  int blk = blockIdx.x, t = threadIdx.x;
  const int* keys; u32t* outc; int E, e0;
  if(blk < K3G){ keys=gi; outc=gcnt_c; E=NNZE; e0=blk*CH3; }
  else         { keys=be; outc=bcnt_c; E=EBI;  e0=(blk-K3G)*CH3; }
  for(int i=t;i<1024;i+=256) h[i]=0;
  __syncthreads();
  for(int i=t;i<CH3;i+=256){
    int e=e0+i;
    if(e<E) atomicAdd(&h[(u32t)keys[e]>>7], 1u);
  }
  __syncthreads();
  for(int b=t;b<1024;b+=256){
    u32t c=h[b];
    if(c) atomicAdd(&outc[b], c);
  }
}

// ---------------- scan coarse counts -> offsets + cursors (2 blocks) ----------------
__global__ __launch_bounds__(256) void scan_coarse_kernel(u32t* __restrict__ gcnt_c,
                                                          u32t* __restrict__ gcoff,
                                                          u32t* __restrict__ gcur_,
                                                          u32t* __restrict__ bcnt_c,
                                                          u32t* __restrict__ bcoff,
                                                          u32t* __restrict__ bcur_){
  __shared__ u32t part[256];
  u32t *cnt, *coff, *cur;
  if(blockIdx.x==0){ cnt=gcnt_c; coff=gcoff; cur=gcur_; }
  else             { cnt=bcnt_c; coff=bcoff; cur=bcur_; }
  int t = threadIdx.x;
  u32t ch[4], s=0;
  #pragma unroll
  for(int j=0;j<4;j++){ int idx=t*4+j; ch[j] = (idx<NBIN)? cnt[idx] : 0u; s+=ch[j]; }
  part[t]=s; __syncthreads();
  for(int off=1;off<256;off<<=1){
    u32t x=(t>=off)?part[t-off]:0u;
    __syncthreads();
    part[t]+=x;
    __syncthreads();
  }
  u32t run=(t==0)?0u:part[t-1];
  #pragma unroll
  for(int j=0;j<4;j++){
    int idx=t*4+j;
    if(idx<NBIN){ coff[idx]=run; cur[idx]=run; run+=ch[j]; }
  }
  if(t==255) coff[NBIN]=part[255];
}

// ---------------- partition: LDS-binned, coalesced bucket writes ----------------
// entry = payload(17b) | (key&127)<<20 | f32val<<32
__global__ __launch_bounds__(256) void part_kernel(const int* __restrict__ gi,
                                                   const float* __restrict__ gv,
                                                   const int* __restrict__ be,
                                                   const float* __restrict__ bv,
                                                   u32t* __restrict__ gcur_,
                                                   u64t* __restrict__ gbuck,
                                                   u32t* __restrict__ bcur_,
                                                   u64t* __restrict__ bbuck){
  __shared__ u32t hist[1024];     // bin counts, then reused as local cursor
  __shared__ u32t scn[1024];      // local exclusive scan
  __shared__ u32t part[256];
  __shared__ u32t base[1024];
  __shared__ u64t ebuf[CH3];
  __shared__ u16t binsArr[CH3];
  int blk = blockIdx.x, t = threadIdx.x;
  const int *keys, *pay; const float* val; u32t* cursor; u64t* buck; int E, e0;
  if(blk < K3G){ keys=gi; pay=gi+NNZE; val=gv; cursor=gcur_; buck=gbuck; E=NNZE; e0=blk*CH3; }
  else         { keys=be; pay=be+EBI;  val=bv; cursor=bcur_; buck=bbuck; E=EBI;  e0=(blk-K3G)*CH3; }
  for(int i=t;i<1024;i+=256) hist[i]=0;
  __syncthreads();
  for(int i=t;i<CH3;i+=256){
    int e=e0+i;
    if(e<E) atomicAdd(&hist[(u32t)keys[e]>>7], 1u);
  }
  __syncthreads();
  // exclusive scan hist[1024] -> scn
  u32t ch[4], s=0;
  #pragma unroll
  for(int j=0;j<4;j++){ ch[j]=hist[t*4+j]; s+=ch[j]; }
  part[t]=s; __syncthreads();
  for(int off=1;off<256;off<<=1){
    u32t x=(t>=off)?part[t-off]:0u;
    __syncthreads();
    part[t]+=x;
    __syncthreads();
  }
  u32t run=(t==0)?0u:part[t-1];
  #pragma unroll
  for(int j=0;j<4;j++){ scn[t*4+j]=run; run+=ch[j]; }
  __syncthreads();
  for(int i=t;i<1024;i+=256) hist[i]=scn[i];   // hist becomes local cursor
  __syncthreads();
  // scatter into LDS, bin-grouped
  for(int i=t;i<CH3;i+=256){
    int e=e0+i;
    if(e<E){
      int k = keys[e];
      u32t b = (u32t)k>>7;
      u32t p = atomicAdd(&hist[b],1u);
      u64t ent = (u64t)((u32t)pay[e] | (((u32t)k&127u)<<20)) | ((u64t)__float_as_uint(val[e])<<32);
      ebuf[p]=ent; binsArr[p]=(u16t)b;
    }
  }
  __syncthreads();
  // reserve global space per bin
  for(int b=t;b<1024;b+=256){
    u32t c = hist[b]-scn[b];
    base[b] = c ? atomicAdd(&cursor[b], c) : 0u;
  }
  __syncthreads();
  // coalesced write-out (consecutive i in a bin -> consecutive global addrs)
  int totalValid = part[255];
  for(int i=t;i<totalValid;i+=256){
    u32t b = binsArr[i];
    buck[ (size_t)base[b] + (u32t)i - scn[b] ] = ebuf[i];
  }
}

// ---------------- GEMM1 (MFMA): xw[N][128] = X[N][256] @ Wg, bf16 out ----------------
__global__ __launch_bounds__(256) void gemm1_kernel(const float* __restrict__ X,
                                                    const u16t* __restrict__ Wg_pre,
                                                    u16t* __restrict__ xwb){
  __shared__ __align__(16) u16t Xs[64*256];   // 32 KB, 8B-granule XOR-swizzled
  const int t = threadIdx.x, l = t & 63, w = t >> 6;
  const int row0 = blockIdx.x * 64;
  for(int i=0;i<16;i++){
    int m = w*16 + i;
    int mg = min(row0 + m, NNODE-1);
    f4v f = __builtin_nontemporal_load((const f4v*)&X[(size_t)mg*DIN + l*4]);
    u32t lo = (u32t)f2bf(f[0]) | ((u32t)f2bf(f[1])<<16);
    u32t hi = (u32t)f2bf(f[2]) | ((u32t)f2bf(f[3])<<16);
    u32t* p = (u32t*)&Xs[m*256 + ((l ^ (m&15))<<2)];
    p[0] = lo; p[1] = hi;
  }
  __syncthreads();
  f32x4 acc[8];
  #pragma unroll
  for(int nf=0;nf<8;nf++) acc[nf] = (f32x4)(0.f);
  const int lm = l & 15, l4 = l >> 4;
  const int mrow = w*16 + lm;
  #pragma unroll 1
  for(int ks=0; ks<8; ks++){
    int kg = ks*8 + l4;
    union { uint2 u2[2]; bf16x8 v; } a;
    a.u2[0] = *(const uint2*)&Xs[mrow*256 + ((kg     ^ lm)<<2)];
    a.u2[1] = *(const uint2*)&Xs[mrow*256 + (((kg+4) ^ lm)<<2)];
    #pragma unroll
    for(int nf=0;nf<8;nf++){
      union { uint4 u4; bf16x8 v; } b;
      b.u4 = *(const uint4*)&Wg_pre[(size_t)((ks*8+nf)*64 + l)*8];
      acc[nf] = __builtin_amdgcn_mfma_f32_16x16x32_bf16(a.v, b.v, acc[nf], 0, 0, 0);
    }
  }
  #pragma unroll
  for(int r=0;r<4;r++){
    int gr = row0 + w*16 + l4*4 + r;
    if(gr < NNODE){
      #pragma unroll
      for(int nf=0;nf<8;nf++)
        xwb[(size_t)gr*HIDN + nf*16 + lm] = f2bf(acc[nf][r]);
    }
  }
}

// ---------------- GCN gather: bin-per-block, in-LDS CSR + gather ----------------
__global__ __launch_bounds__(256) void gcn_gather2_kernel(const u16t* __restrict__ xwb,
                                                          const u64t* __restrict__ gbuck,
                                                          const u32t* __restrict__ gcoff,
                                                          u32t* __restrict__ hiddenw){
  __shared__ u64t ebuf[CAPG];
  __shared__ u32t hist[128], offs[129], cur[128], sc[128];
  int bin = blockIdx.x, t = threadIdx.x;
  u32t base = gcoff[bin], cnt = gcoff[bin+1] - base;
  if(t<128) hist[t]=0;
  __syncthreads();
  for(u32t i=t;i<cnt;i+=256)
    atomicAdd(&hist[(u32t)(gbuck[base+i]>>20)&127u], 1u);
  __syncthreads();
  if(t<128) sc[t]=hist[t];
  __syncthreads();
  for(int off=1;off<128;off<<=1){
    u32t x=(t>=off&&t<128)?sc[t-off]:0u;
    __syncthreads();
    if(t<128) sc[t]+=x;
    __syncthreads();
  }
  if(t<128){ offs[t+1]=sc[t]; cur[t]=sc[t]-hist[t]; if(t==0) offs[0]=0u; }
  __syncthreads();
  for(u32t i=t;i<cnt;i+=256){
    u64t e = gbuck[base+i];
    u32t p = atomicAdd(&cur[(u32t)(e>>20)&127u], 1u);
    ebuf[p]=e;
  }
  __syncthreads();
  int w=t>>6, l=t&63;
  const u32t* xww=(const u32t*)xwb;
  for(int idx=w; idx<128; idx+=4){
    int n = bin*128 + idx;
    if(n >= NNODE) continue;
    u32t s0=offs[idx], cnt2=offs[idx+1]-s0;
    float acc0=0.f, acc1=0.f;
    u32t nbr=(cnt2+3)&~3u;
    for(u32t j=0;j<nbr;j+=4){
      float2 xs[4]; float vs[4];
      #pragma unroll
      for(int q=0;q<4;q++){
        u32t jj=j+q;
        u64t e=(jj<cnt2)? ebuf[s0+jj] : 0ULL;
        vs[q]=__uint_as_float((u32t)(e>>32));
        xs[q]=up2(xww[(size_t)(e&0x1FFFFu)*64 + l]);
      }
      #pragma unroll
      for(int q=0;q<4;q++){ acc0+=vs[q]*xs[q].x; acc1+=vs[q]*xs[q].y; }
    }
    hiddenw[(size_t)n*64 + l] = (u32t)f2bf(acc0) | ((u32t)f2bf(acc1)<<16);
  }
}

// ---------------- GEMM2 (MFMA): SRCw (in-place over hiddenw) + DSTw ----------------
__global__ __launch_bounds__(256) void gemm2_kernel(u32t* __restrict__ hiddenw,
                                                    const u16t* __restrict__ Wc_pre,
                                                    u16t* __restrict__ DSTw){
  __shared__ __align__(16) u16t Hs[64*128];   // 16 KB
  const int t = threadIdx.x, l = t & 63, w = t >> 6;
  const int row0 = blockIdx.x * 64;
  for(int i=0;i<16;i++){
    int m = w*16 + i;
    int mg = min(row0 + m, NNODE-1);
    u32t v = hiddenw[(size_t)mg*64 + l];
    *(u32t*)&Hs[m*128 + (((l>>1) ^ (m&15))<<2) + ((l&1)<<1)] = v;
  }
  __syncthreads();
  f32x4 acc[16];
  #pragma unroll
  for(int nf=0;nf<16;nf++) acc[nf] = (f32x4)(0.f);
  const int lm = l & 15, l4 = l >> 4;
  const int mrow = w*16 + lm;
  #pragma unroll 1
  for(int ks=0; ks<4; ks++){
    int kg = ks*8 + l4;
    union { uint2 u2[2]; bf16x8 v; } a;
    a.u2[0] = *(const uint2*)&Hs[mrow*128 + ((kg     ^ lm)<<2)];
    a.u2[1] = *(const uint2*)&Hs[mrow*128 + (((kg+4) ^ lm)<<2)];
    #pragma unroll
    for(int nf=0;nf<16;nf++){
      union { uint4 u4; bf16x8 v; } b;
      b.u4 = *(const uint4*)&Wc_pre[(size_t)((ks*16+nf)*64 + l)*8];
      acc[nf] = __builtin_amdgcn_mfma_f32_16x16x32_bf16(a.v, b.v, acc[nf], 0, 0, 0);
    }
  }
  u16t* SRCw = (u16t*)hiddenw;   // in-place: this block's rows were staged above
  #pragma unroll
  for(int r=0;r<4;r++){
    int gr = row0 + w*16 + l4*4 + r;
    if(gr < NNODE){
      #pragma unroll
      for(int nf=0;nf<8;nf++)
        SRCw[(size_t)gr*HIDN + nf*16 + lm] = f2bf(acc[nf][r]);
      #pragma unroll
      for(int nf=8;nf<16;nf++)
        DSTw[(size_t)gr*HIDN + (nf-8)*16 + lm] = f2bf(acc[nf][r]);
    }
  }
}

// ---------------- directed-edge heads: 4 edges per wave ----------------
__global__ __launch_bounds__(256) void edge_kernel(const u16t* __restrict__ SRCb,
                                                   const u16t* __restrict__ DSTb,
                                                   const int*  __restrict__ ed,
                                                   const float* __restrict__ nin,
                                                   const float* __restrict__ nout,
                                                   float* __restrict__ ein,
                                                   float* __restrict__ eout){
  const int e0 = (blockIdx.x*4 + (threadIdx.x>>6))*4;
  const int l = threadIdx.x & 63;
  const u32t* Sw = (const u32t*)SRCb;
  const u32t* Dw = (const u32t*)DSTb;
  int s[4], d[4];
  #pragma unroll
  for(int q=0;q<4;q++){ s[q] = ed[e0+q]; d[q] = ed[EDIR+e0+q]; }
  float2 Ss[4], Ds[4], Sd[4], Dd[4];
  float ni[4], no[4];
  #pragma unroll
  for(int q=0;q<4;q++){
    Ss[q] = up2(Sw[(size_t)s[q]*64 + l]);
    Ds[q] = up2(Dw[(size_t)s[q]*64 + l]);
    Sd[q] = up2(Sw[(size_t)d[q]*64 + l]);
    Dd[q] = up2(Dw[(size_t)d[q]*64 + l]);
    ni[q] = __builtin_nontemporal_load(&nin[(size_t)(e0+q)*DOUTN + l]);
    no[q] = __builtin_nontemporal_load(&nout[(size_t)(e0+q)*DOUTN + l]);
  }
  #pragma unroll
  for(int q=0;q<4;q++){
    size_t o = (size_t)(e0+q)*DOUTN + l;
    float miu_in  = Ss[q].x + Dd[q].x, ls_in  = Ss[q].y + Dd[q].y;
    float miu_out = Sd[q].x + Ds[q].x, ls_out = Sd[q].y + Ds[q].y;
    __builtin_nontemporal_store(ni[q] * __expf(ls_in)  + miu_in,  &ein[o]);
    __builtin_nontemporal_store(no[q] * __expf(ls_out) + miu_out, &eout[o]);
  }
}

// ---------------- BI gather: bin-per-block, in-LDS CSR + gather + finalize ----------------
__global__ __launch_bounds__(256) void bi_gather2_kernel(const u16t* __restrict__ SRCb,
                                                         const u16t* __restrict__ DSTb,
                                                         const u64t* __restrict__ bbuck,
                                                         const u32t* __restrict__ bcoff,
                                                         const float* __restrict__ nn,
                                                         float* __restrict__ outp){
  __shared__ u64t ebuf[CAPB];
  __shared__ u32t hist[128], offs[129], cur[128], sc[128];
  int bin = blockIdx.x, t = threadIdx.x;
  u32t base = bcoff[bin], cnt = bcoff[bin+1] - base;
  if(t<128) hist[t]=0;
  __syncthreads();
  for(u32t i=t;i<cnt;i+=256)
    atomicAdd(&hist[(u32t)(bbuck[base+i]>>20)&127u], 1u);
  __syncthreads();
  if(t<128) sc[t]=hist[t];
  __syncthreads();
  for(int off=1;off<128;off<<=1){
    u32t x=(t>=off&&t<128)?sc[t-off]:0u;
    __syncthreads();
    if(t<128) sc[t]+=x;
    __syncthreads();
  }
  if(t<128){ offs[t+1]=sc[t]; cur[t]=sc[t]-hist[t]; if(t==0) offs[0]=0u; }
  __syncthreads();
  for(u32t i=t;i<cnt;i+=256){
    u64t e = bbuck[base+i];
    u32t p = atomicAdd(&cur[(u32t)(e>>20)&127u], 1u);
    ebuf[p]=e;
  }
  __syncthreads();
  int w=t>>6, l=t&63;
  const u32t* Sw=(const u32t*)SRCb;
  const u32t* Dw=(const u32t*)DSTb;
  for(int idx=w; idx<128; idx+=4){
    int n = bin*128 + idx;
    if(n >= NNODE) continue;
    float2 S = up2(Sw[(size_t)n*64 + l]);
    u32t s0=offs[idx], cnt2=offs[idx+1]-s0;
    float nmiu=0.f, nvar=0.f;
    u32t nbr=(cnt2+3)&~3u;
    for(u32t j=0;j<nbr;j+=4){
      float2 Dq[4]; float vs[4];
      #pragma unroll
      for(int q=0;q<4;q++){
        u32t jj=j+q;
        u64t e=(jj<cnt2)? ebuf[s0+jj] : 0ULL;
        vs[q]=__uint_as_float((u32t)(e>>32));
        Dq[q]=up2(Dw[(size_t)(e&0x1FFFFu)*64 + l]);
      }
      #pragma unroll
      for(int q=0;q<4;q++){
        nmiu += vs[q]*(S.x+Dq[q].x);
        nvar += vs[q]*vs[q]*__expf(S.y+Dq[q].y);
      }
    }
    size_t o = (size_t)n*DOUTN + l;
    float nd = __builtin_nontemporal_load(&nn[o]);
    __builtin_nontemporal_store(nd*sqrtf(nvar) + nmiu, &outp[o]);  // exp(0.5*log v)==sqrt(v)
  }
}

extern "C" void kernel_launch(void* const* d_in, const int* in_sizes, int n_in,
                              void* d_out, int out_size, void* d_ws, size_t ws_size,
                              hipStream_t stream){
  const float* X    = (const float*)d_in[0];
  const float* Wg   = (const float*)d_in[1];
  const float* Wm   = (const float*)d_in[2];
  const float* Wsg  = (const float*)d_in[3];
  const float* gv   = (const float*)d_in[4];
  const float* bv   = (const float*)d_in[5];
  const float* nin  = (const float*)d_in[6];
  const float* nout = (const float*)d_in[7];
  const float* nnod = (const float*)d_in[8];
  const int*  gi   = (const int*)d_in[9];
  const int*  ed   = (const int*)d_in[10];
  const int*  be   = (const int*)d_in[11];

  // workspace (76.8 MB):
  //  [0,12.8M)        gbuck u64            -> phase2: DSTw bf16 [0,25.6M)
  //  [12.8M,38.4M)    xwb bf16             -> (tail of DSTw)
  //  [38.4M,+24K)     coarse meta: gcnt_c|bcnt_c|gcoff|gcur_|bcoff|bcur_ (1024 u32 each)
  //  [40.0M,48.0M)    bbuck u64 (lives until bi_gather2)
  //  [51.2M,76.8M)    hiddenw u32-packed bf16 -> in-place SRCw bf16 after gemm2
  char* ws = (char*)d_ws;
  u64t*  gbuck   = (u64t*)ws;
  u16t*  xwb     = (u16t*)(ws + 12800000);
  u32t*  gcnt_c  = (u32t*)(ws + 38400000);
  u32t*  bcnt_c  = (u32t*)(ws + 38404096);
  u32t*  gcoff   = (u32t*)(ws + 38408192);
  u32t*  gcur_   = (u32t*)(ws + 38412288);
  u32t*  bcoff   = (u32t*)(ws + 38416384);
  u32t*  bcur_   = (u32t*)(ws + 38420480);
  u64t*  bbuck   = (u64t*)(ws + 40003168);
  u32t*  hiddenw = (u32t*)(ws + 51200000);
  u16t*  SRCw    = (u16t*)hiddenw;
  u16t*  DSTw    = (u16t*)ws;

  float* out  = (float*)d_out;
  float* ein  = out + (size_t)NNODE*DOUTN;
  float* eout = ein + (size_t)EDIR*DOUTN;
  // weight-prep arrays in tail of d_out's node region; dead before bi_gather2 overwrites
  u16t* Wg_pre = (u16t*)((char*)d_out + 25600000 - 131072);
  u16t* Wc_pre = Wg_pre + 32768;

  (void)hipMemsetAsync(gcnt_c, 0, 8192, stream);                // gcnt_c + bcnt_c
  coarse_hist_kernel<<<K3G+K3B, 256, 0, stream>>>(gi, be, gcnt_c, bcnt_c);
  scan_coarse_kernel<<<2,       256, 0, stream>>>(gcnt_c, gcoff, gcur_, bcnt_c, bcoff, bcur_);
  part_kernel       <<<K3G+K3B, 256, 0, stream>>>(gi, gv, be, bv, gcur_, gbuck, bcur_, bbuck);
  prep_kernel       <<<256,     256, 0, stream>>>(Wg, Wm, Wsg, Wg_pre, Wc_pre);
  gemm1_kernel      <<<G64,     256, 0, stream>>>(X, Wg_pre, xwb);
  gcn_gather2_kernel<<<NBIN,    256, 0, stream>>>(xwb, gbuck, gcoff, hiddenw);
  gemm2_kernel      <<<G64,     256, 0, stream>>>(hiddenw, Wc_pre, DSTw);
  edge_kernel       <<<EDIR/16, 256, 0, stream>>>(SRCw, DSTw, ed, nin, nout, ein, eout);
  bi_gather2_kernel <<<NBIN,    256, 0, stream>>>(SRCw, DSTw, bbuck, bcoff, nnod, out);
}

// Round 14
// 446.658 us; speedup vs baseline: 1.4811x; 1.0836x over previous
//
#include <hip/hip_runtime.h>

typedef unsigned short u16t;
typedef unsigned int   u32t;
typedef unsigned long long u64t;

#define NNODE 100000
#define DIN   256
#define HIDN  128
#define DOUTN 64
#define NNZE  1600000
#define EDIR  500000
#define EBI   1000000
#define G64   1563           // ceil(NNODE/64)
#define NBIN  782            // ceil(NNODE/128), bin = key>>7
#define CH3   4096           // edges per partition block
#define K3G   391            // ceil(NNZE/CH3)
#define K3B   245            // ceil(EBI/CH3)
#define CAPG  2432           // gcn entries per bin cap (mean 2048, sd 45 -> 8.5 sigma)
#define CAPB  1536           // bi entries per bin cap (mean 1280, sd 34 -> 7.5 sigma)
#define EBLK  15625          // EDIR/32: edge blocks (8 edges/wave, 4 waves)

typedef __attribute__((ext_vector_type(8))) short bf16x8;
typedef __attribute__((ext_vector_type(4))) float f32x4;
typedef __attribute__((ext_vector_type(4))) float f4v;

__device__ __forceinline__ u16t f2bf(float f){
  u32t u = __float_as_uint(f);
  u += 0x7FFFu + ((u>>16)&1u);          // round-to-nearest-even
  return (u16t)(u>>16);
}
__device__ __forceinline__ float2 up2(u32t w){
  return make_float2(__uint_as_float(w<<16), __uint_as_float(w&0xFFFF0000u));
}

// ---------------- weight prep: fragment-ready bf16 layouts ----------------
__global__ __launch_bounds__(256) void prep_kernel(const float* __restrict__ Wg,
                                                   const float* __restrict__ Wm,
                                                   const float* __restrict__ Wsg,
                                                   u16t* __restrict__ Wg_pre,
                                                   u16t* __restrict__ Wc_pre){
  int idx = blockIdx.x*256 + threadIdx.x;       // 0..65535
  int e = idx & 7, l = (idx>>3) & 63, f = (idx>>9) & 63, sel = idx>>15;
  int k_in = ((e>>2)<<4) + ((l>>4)<<2) + (e&3);
  if(sel == 0){
    int ks = f>>3, nf = f&7;
    int k = ks*32 + k_in, n = nf*16 + (l&15);
    Wg_pre[idx] = f2bf(Wg[(size_t)k*HIDN + n]);
  } else {
    int ks = f>>4, nf = f&15;
    int k = ks*32 + k_in, c = nf*16 + (l&15);
    int half = c>>7, ci = c&127;
    const float* src = (ci&1) ? Wsg : Wm;
    Wc_pre[idx - 32768] = f2bf(src[(size_t)(half*128 + k)*DOUTN + (ci>>1)]);
  }
}

// ---------------- coarse histogram over 782 bins, both streams ----------------
__global__ __launch_bounds__(256) void coarse_hist_kernel(const int* __restrict__ gi,
                                                          const int* __restrict__ be,
                                                          u32t* __restrict__ gcnt_c,
                                                          u32t* __restrict__ bcnt_c){
  __shared__ u32t h[1024];
  int blk = blockIdx.x, t = threadIdx.x;
  const int* keys; u32t* outc; int E, e0;
  if(blk < K3G){ keys=gi; outc=gcnt_c; E=NNZE; e0=blk*CH3; }
  else         { keys=be; outc=bcnt_c; E=EBI;  e0=(blk-K3G)*CH3; }
  for(int i=t;i<1024;i+=256) h[i]=0;
  __syncthreads();
  for(int i=t;i<CH3;i+=256){
    int e=e0+i;
    if(e<E) atomicAdd(&h[(u32t)keys[e]>>7], 1u);
  }
  __syncthreads();
  for(int b=t;b<1024;b+=256){
    u32t c=h[b];
    if(c) atomicAdd(&outc[b], c);
  }
}

// ---------------- scan coarse counts -> offsets + cursors (2 blocks) ----------------
__global__ __launch_bounds__(256) void scan_coarse_kernel(u32t* __restrict__ gcnt_c,
                                                          u32t* __restrict__ gcoff,
                                                          u32t* __restrict__ gcur_,
                                                          u32t* __restrict__ bcnt_c,
                                                          u32t* __restrict__ bcoff,
                                                          u32t* __restrict__ bcur_){
  __shared__ u32t part[256];
  u32t *cnt, *coff, *cur;
  if(blockIdx.x==0){ cnt=gcnt_c; coff=gcoff; cur=gcur_; }
  else             { cnt=bcnt_c; coff=bcoff; cur=bcur_; }
  int t = threadIdx.x;
  u32t ch[4], s=0;
  #pragma unroll
  for(int j=0;j<4;j++){ int idx=t*4+j; ch[j] = (idx<NBIN)? cnt[idx] : 0u; s+=ch[j]; }
  part[t]=s; __syncthreads();
  for(int off=1;off<256;off<<=1){
    u32t x=(t>=off)?part[t-off]:0u;
    __syncthreads();
    part[t]+=x;
    __syncthreads();
  }
  u32t run=(t==0)?0u:part[t-1];
  #pragma unroll
  for(int j=0;j<4;j++){
    int idx=t*4+j;
    if(idx<NBIN){ coff[idx]=run; cur[idx]=run; run+=ch[j]; }
  }
  if(t==255) coff[NBIN]=part[255];
}

// ---------------- partition: LDS-binned, coalesced bucket writes ----------------
// entry = payload(17b) | (key&127)<<20 | f32val<<32
__global__ __launch_bounds__(256) void part_kernel(const int* __restrict__ gi,
                                                   const float* __restrict__ gv,
                                                   const int* __restrict__ be,
                                                   const float* __restrict__ bv,
                                                   u32t* __restrict__ gcur_,
                                                   u64t* __restrict__ gbuck,
                                                   u32t* __restrict__ bcur_,
                                                   u64t* __restrict__ bbuck){
  __shared__ u32t hist[1024];     // bin counts, then reused as local cursor
  __shared__ u32t scn[1024];      // local exclusive scan
  __shared__ u32t part[256];
  __shared__ u32t base[1024];
  __shared__ u64t ebuf[CH3];
  __shared__ u16t binsArr[CH3];
  int blk = blockIdx.x, t = threadIdx.x;
  const int *keys, *pay; const float* val; u32t* cursor; u64t* buck; int E, e0;
  if(blk < K3G){ keys=gi; pay=gi+NNZE; val=gv; cursor=gcur_; buck=gbuck; E=NNZE; e0=blk*CH3; }
  else         { keys=be; pay=be+EBI;  val=bv; cursor=bcur_; buck=bbuck; E=EBI;  e0=(blk-K3G)*CH3; }
  for(int i=t;i<1024;i+=256) hist[i]=0;
  __syncthreads();
  for(int i=t;i<CH3;i+=256){
    int e=e0+i;
    if(e<E) atomicAdd(&hist[(u32t)keys[e]>>7], 1u);
  }
  __syncthreads();
  // exclusive scan hist[1024] -> scn
  u32t ch[4], s=0;
  #pragma unroll
  for(int j=0;j<4;j++){ ch[j]=hist[t*4+j]; s+=ch[j]; }
  part[t]=s; __syncthreads();
  for(int off=1;off<256;off<<=1){
    u32t x=(t>=off)?part[t-off]:0u;
    __syncthreads();
    part[t]+=x;
    __syncthreads();
  }
  u32t run=(t==0)?0u:part[t-1];
  #pragma unroll
  for(int j=0;j<4;j++){ scn[t*4+j]=run; run+=ch[j]; }
  __syncthreads();
  for(int i=t;i<1024;i+=256) hist[i]=scn[i];   // hist becomes local cursor
  __syncthreads();
  // scatter into LDS, bin-grouped
  for(int i=t;i<CH3;i+=256){
    int e=e0+i;
    if(e<E){
      int k = keys[e];
      u32t b = (u32t)k>>7;
      u32t p = atomicAdd(&hist[b],1u);
      u64t ent = (u64t)((u32t)pay[e] | (((u32t)k&127u)<<20)) | ((u64t)__float_as_uint(val[e])<<32);
      ebuf[p]=ent; binsArr[p]=(u16t)b;
    }
  }
  __syncthreads();
  // reserve global space per bin
  for(int b=t;b<1024;b+=256){
    u32t c = hist[b]-scn[b];
    base[b] = c ? atomicAdd(&cursor[b], c) : 0u;
  }
  __syncthreads();
  // coalesced write-out (consecutive i in a bin -> consecutive global addrs)
  int totalValid = part[255];
  for(int i=t;i<totalValid;i+=256){
    u32t b = binsArr[i];
    buck[ (size_t)base[b] + (u32t)i - scn[b] ] = ebuf[i];
  }
}

// ---------------- GEMM1 (MFMA): xw[N][128] = X[N][256] @ Wg, bf16 out ----------------
__global__ __launch_bounds__(256) void gemm1_kernel(const float* __restrict__ X,
                                                    const u16t* __restrict__ Wg_pre,
                                                    u16t* __restrict__ xwb){
  __shared__ __align__(16) u16t Xs[64*256];   // 32 KB, 8B-granule XOR-swizzled
  const int t = threadIdx.x, l = t & 63, w = t >> 6;
  const int row0 = blockIdx.x * 64;
  for(int i=0;i<16;i++){
    int m = w*16 + i;
    int mg = min(row0 + m, NNODE-1);
    f4v f = __builtin_nontemporal_load((const f4v*)&X[(size_t)mg*DIN + l*4]);
    u32t lo = (u32t)f2bf(f[0]) | ((u32t)f2bf(f[1])<<16);
    u32t hi = (u32t)f2bf(f[2]) | ((u32t)f2bf(f[3])<<16);
    u32t* p = (u32t*)&Xs[m*256 + ((l ^ (m&15))<<2)];
    p[0] = lo; p[1] = hi;
  }
  __syncthreads();
  f32x4 acc[8];
  #pragma unroll
  for(int nf=0;nf<8;nf++) acc[nf] = (f32x4)(0.f);
  const int lm = l & 15, l4 = l >> 4;
  const int mrow = w*16 + lm;
  #pragma unroll 1
  for(int ks=0; ks<8; ks++){
    int kg = ks*8 + l4;
    union { uint2 u2[2]; bf16x8 v; } a;
    a.u2[0] = *(const uint2*)&Xs[mrow*256 + ((kg     ^ lm)<<2)];
    a.u2[1] = *(const uint2*)&Xs[mrow*256 + (((kg+4) ^ lm)<<2)];
    #pragma unroll
    for(int nf=0;nf<8;nf++){
      union { uint4 u4; bf16x8 v; } b;
      b.u4 = *(const uint4*)&Wg_pre[(size_t)((ks*8+nf)*64 + l)*8];
      acc[nf] = __builtin_amdgcn_mfma_f32_16x16x32_bf16(a.v, b.v, acc[nf], 0, 0, 0);
    }
  }
  #pragma unroll
  for(int r=0;r<4;r++){
    int gr = row0 + w*16 + l4*4 + r;
    if(gr < NNODE){
      #pragma unroll
      for(int nf=0;nf<8;nf++)
        xwb[(size_t)gr*HIDN + nf*16 + lm] = f2bf(acc[nf][r]);
    }
  }
}

// ---------------- GCN gather: bin-per-block, in-LDS CSR + gather ----------------
__global__ __launch_bounds__(256) void gcn_gather2_kernel(const u16t* __restrict__ xwb,
                                                          const u64t* __restrict__ gbuck,
                                                          const u32t* __restrict__ gcoff,
                                                          u32t* __restrict__ hiddenw){
  __shared__ u64t ebuf[CAPG];
  __shared__ u32t hist[128], offs[129], cur[128], sc[128];
  int bin = blockIdx.x, t = threadIdx.x;
  u32t base = gcoff[bin], cnt = gcoff[bin+1] - base;
  if(t<128) hist[t]=0;
  __syncthreads();
  for(u32t i=t;i<cnt;i+=256)
    atomicAdd(&hist[(u32t)(gbuck[base+i]>>20)&127u], 1u);
  __syncthreads();
  if(t<128) sc[t]=hist[t];
  __syncthreads();
  for(int off=1;off<128;off<<=1){
    u32t x=(t>=off&&t<128)?sc[t-off]:0u;
    __syncthreads();
    if(t<128) sc[t]+=x;
    __syncthreads();
  }
  if(t<128){ offs[t+1]=sc[t]; cur[t]=sc[t]-hist[t]; if(t==0) offs[0]=0u; }
  __syncthreads();
  for(u32t i=t;i<cnt;i+=256){
    u64t e = gbuck[base+i];
    u32t p = atomicAdd(&cur[(u32t)(e>>20)&127u], 1u);
    ebuf[p]=e;
  }
  __syncthreads();
  int w=t>>6, l=t&63;
  const u32t* xww=(const u32t*)xwb;
  for(int idx=w; idx<128; idx+=4){
    int n = bin*128 + idx;
    if(n >= NNODE) continue;
    u32t s0=offs[idx], cnt2=offs[idx+1]-s0;
    float acc0=0.f, acc1=0.f;
    u32t nbr=(cnt2+3)&~3u;
    for(u32t j=0;j<nbr;j+=4){
      float2 xs[4]; float vs[4];
      #pragma unroll
      for(int q=0;q<4;q++){
        u32t jj=j+q;
        u64t e=(jj<cnt2)? ebuf[s0+jj] : 0ULL;
        vs[q]=__uint_as_float((u32t)(e>>32));
        xs[q]=up2(xww[(size_t)(e&0x1FFFFu)*64 + l]);
      }
      #pragma unroll
      for(int q=0;q<4;q++){ acc0+=vs[q]*xs[q].x; acc1+=vs[q]*xs[q].y; }
    }
    hiddenw[(size_t)n*64 + l] = (u32t)f2bf(acc0) | ((u32t)f2bf(acc1)<<16);
  }
}

// ---------------- GEMM2 (MFMA): SRCw (in-place over hiddenw) + DSTw ----------------
__global__ __launch_bounds__(256) void gemm2_kernel(u32t* __restrict__ hiddenw,
                                                    const u16t* __restrict__ Wc_pre,
                                                    u16t* __restrict__ DSTw){
  __shared__ __align__(16) u16t Hs[64*128];   // 16 KB
  const int t = threadIdx.x, l = t & 63, w = t >> 6;
  const int row0 = blockIdx.x * 64;
  for(int i=0;i<16;i++){
    int m = w*16 + i;
    int mg = min(row0 + m, NNODE-1);
    u32t v = hiddenw[(size_t)mg*64 + l];
    *(u32t*)&Hs[m*128 + (((l>>1) ^ (m&15))<<2) + ((l&1)<<1)] = v;
  }
  __syncthreads();
  f32x4 acc[16];
  #pragma unroll
  for(int nf=0;nf<16;nf++) acc[nf] = (f32x4)(0.f);
  const int lm = l & 15, l4 = l >> 4;
  const int mrow = w*16 + lm;
  #pragma unroll 1
  for(int ks=0; ks<4; ks++){
    int kg = ks*8 + l4;
    union { uint2 u2[2]; bf16x8 v; } a;
    a.u2[0] = *(const uint2*)&Hs[mrow*128 + ((kg     ^ lm)<<2)];
    a.u2[1] = *(const uint2*)&Hs[mrow*128 + (((kg+4) ^ lm)<<2)];
    #pragma unroll
    for(int nf=0;nf<16;nf++){
      union { uint4 u4; bf16x8 v; } b;
      b.u4 = *(const uint4*)&Wc_pre[(size_t)((ks*16+nf)*64 + l)*8];
      acc[nf] = __builtin_amdgcn_mfma_f32_16x16x32_bf16(a.v, b.v, acc[nf], 0, 0, 0);
    }
  }
  u16t* SRCw = (u16t*)hiddenw;   // in-place: this block's rows were staged above
  #pragma unroll
  for(int r=0;r<4;r++){
    int gr = row0 + w*16 + l4*4 + r;
    if(gr < NNODE){
      #pragma unroll
      for(int nf=0;nf<8;nf++)
        SRCw[(size_t)gr*HIDN + nf*16 + lm] = f2bf(acc[nf][r]);
      #pragma unroll
      for(int nf=8;nf<16;nf++)
        DSTw[(size_t)gr*HIDN + (nf-8)*16 + lm] = f2bf(acc[nf][r]);
    }
  }
}

// ---------------- union kernel: bi bins (blocks [0,NBIN)) + edge heads (8 edges/wave) ----------------
__global__ __launch_bounds__(256) void edgebi2_kernel(const u16t* __restrict__ SRCb,
                                                      const u16t* __restrict__ DSTb,
                                                      const int*  __restrict__ ed,
                                                      const float* __restrict__ nin,
                                                      const float* __restrict__ nout,
                                                      float* __restrict__ ein,
                                                      float* __restrict__ eout,
                                                      const u64t* __restrict__ bbuck,
                                                      const u32t* __restrict__ bcoff,
                                                      const float* __restrict__ nn,
                                                      float* __restrict__ outp){
  __shared__ u64t ebuf[CAPB];
  __shared__ u32t hist[128], offs[129], cur[128], sc[128];
  const int t = threadIdx.x;
  const u32t* Sw = (const u32t*)SRCb;
  const u32t* Dw = (const u32t*)DSTb;
  if(blockIdx.x >= NBIN){
    // ---------- edge path: 8 edges per wave ----------
    const int e0 = ((int)(blockIdx.x - NBIN)*4 + (t>>6))*8;
    const int l = t & 63;
    int s[8], d[8];
    #pragma unroll
    for(int q=0;q<8;q++){ s[q] = ed[e0+q]; d[q] = ed[EDIR+e0+q]; }
    float2 Ss[8], Ds[8], Sd[8], Dd[8];
    float ni[8], no[8];
    #pragma unroll
    for(int q=0;q<8;q++){
      Ss[q] = up2(Sw[(size_t)s[q]*64 + l]);
      Ds[q] = up2(Dw[(size_t)s[q]*64 + l]);
      Sd[q] = up2(Sw[(size_t)d[q]*64 + l]);
      Dd[q] = up2(Dw[(size_t)d[q]*64 + l]);
      ni[q] = __builtin_nontemporal_load(&nin[(size_t)(e0+q)*DOUTN + l]);
      no[q] = __builtin_nontemporal_load(&nout[(size_t)(e0+q)*DOUTN + l]);
    }
    #pragma unroll
    for(int q=0;q<8;q++){
      size_t o = (size_t)(e0+q)*DOUTN + l;
      float miu_in  = Ss[q].x + Dd[q].x, ls_in  = Ss[q].y + Dd[q].y;
      float miu_out = Sd[q].x + Ds[q].x, ls_out = Sd[q].y + Ds[q].y;
      __builtin_nontemporal_store(ni[q] * __expf(ls_in)  + miu_in,  &ein[o]);
      __builtin_nontemporal_store(no[q] * __expf(ls_out) + miu_out, &eout[o]);
    }
    return;
  }
  // ---------- bi path: bin-per-block in-LDS CSR + gather + finalize ----------
  int bin = blockIdx.x;
  u32t base = bcoff[bin], cnt = bcoff[bin+1] - base;
  if(t<128) hist[t]=0;
  __syncthreads();
  for(u32t i=t;i<cnt;i+=256)
    atomicAdd(&hist[(u32t)(bbuck[base+i]>>20)&127u], 1u);
  __syncthreads();
  if(t<128) sc[t]=hist[t];
  __syncthreads();
  for(int off=1;off<128;off<<=1){
    u32t x=(t>=off&&t<128)?sc[t-off]:0u;
    __syncthreads();
    if(t<128) sc[t]+=x;
    __syncthreads();
  }
  if(t<128){ offs[t+1]=sc[t]; cur[t]=sc[t]-hist[t]; if(t==0) offs[0]=0u; }
  __syncthreads();
  for(u32t i=t;i<cnt;i+=256){
    u64t e = bbuck[base+i];
    u32t p = atomicAdd(&cur[(u32t)(e>>20)&127u], 1u);
    ebuf[p]=e;
  }
  __syncthreads();
  int w=t>>6, l=t&63;
  for(int idx=w; idx<128; idx+=4){
    int n = bin*128 + idx;
    if(n >= NNODE) continue;
    float2 S = up2(Sw[(size_t)n*64 + l]);
    u32t s0=offs[idx], cnt2=offs[idx+1]-s0;
    float nmiu=0.f, nvar=0.f;
    u32t nbr=(cnt2+3)&~3u;
    for(u32t j=0;j<nbr;j+=4){
      float2 Dq[4]; float vs[4];
      #pragma unroll
      for(int q=0;q<4;q++){
        u32t jj=j+q;
        u64t e=(jj<cnt2)? ebuf[s0+jj] : 0ULL;
        vs[q]=__uint_as_float((u32t)(e>>32));
        Dq[q]=up2(Dw[(size_t)(e&0x1FFFFu)*64 + l]);
      }
      #pragma unroll
      for(int q=0;q<4;q++){
        nmiu += vs[q]*(S.x+Dq[q].x);
        nvar += vs[q]*vs[q]*__expf(S.y+Dq[q].y);
      }
    }
    size_t o = (size_t)n*DOUTN + l;
    float nd = __builtin_nontemporal_load(&nn[o]);
    __builtin_nontemporal_store(nd*sqrtf(nvar) + nmiu, &outp[o]);  // exp(0.5*log v)==sqrt(v)
  }
}

extern "C" void kernel_launch(void* const* d_in, const int* in_sizes, int n_in,
                              void* d_out, int out_size, void* d_ws, size_t ws_size,
                              hipStream_t stream){
  const float* X    = (const float*)d_in[0];
  const float* Wg   = (const float*)d_in[1];
  const float* Wm   = (const float*)d_in[2];
  const float* Wsg  = (const float*)d_in[3];
  const float* gv   = (const float*)d_in[4];
  const float* bv   = (const float*)d_in[5];
  const float* nin  = (const float*)d_in[6];
  const float* nout = (const float*)d_in[7];
  const float* nnod = (const float*)d_in[8];
  const int*  gi   = (const int*)d_in[9];
  const int*  ed   = (const int*)d_in[10];
  const int*  be   = (const int*)d_in[11];

  // workspace (76.8 MB):
  //  [0,12.8M)        gbuck u64            -> phase2: DSTw bf16 [0,25.6M)
  //  [12.8M,38.4M)    xwb bf16             -> (tail of DSTw)
  //  [38.4M,+24K)     coarse meta: gcnt_c|bcnt_c|gcoff|gcur_|bcoff|bcur_ (1024 u32 each)
  //  [40.0M,48.0M)    bbuck u64 (lives until edgebi2)
  //  [51.2M,76.8M)    hiddenw u32-packed bf16 -> in-place SRCw bf16 after gemm2
  char* ws = (char*)d_ws;
  u64t*  gbuck   = (u64t*)ws;
  u16t*  xwb     = (u16t*)(ws + 12800000);
  u32t*  gcnt_c  = (u32t*)(ws + 38400000);
  u32t*  bcnt_c  = (u32t*)(ws + 38404096);
  u32t*  gcoff   = (u32t*)(ws + 38408192);
  u32t*  gcur_   = (u32t*)(ws + 38412288);
  u32t*  bcoff   = (u32t*)(ws + 38416384);
  u32t*  bcur_   = (u32t*)(ws + 38420480);
  u64t*  bbuck   = (u64t*)(ws + 40003168);
  u32t*  hiddenw = (u32t*)(ws + 51200000);
  u16t*  SRCw    = (u16t*)hiddenw;
  u16t*  DSTw    = (u16t*)ws;

  float* out  = (float*)d_out;
  float* ein  = out + (size_t)NNODE*DOUTN;
  float* eout = ein + (size_t)EDIR*DOUTN;
  // weight-prep arrays in tail of d_out's node region; dead before edgebi2 overwrites
  u16t* Wg_pre = (u16t*)((char*)d_out + 25600000 - 131072);
  u16t* Wc_pre = Wg_pre + 32768;

  (void)hipMemsetAsync(gcnt_c, 0, 8192, stream);                // gcnt_c + bcnt_c
  coarse_hist_kernel<<<K3G+K3B, 256, 0, stream>>>(gi, be, gcnt_c, bcnt_c);
  scan_coarse_kernel<<<2,       256, 0, stream>>>(gcnt_c, gcoff, gcur_, bcnt_c, bcoff, bcur_);
  part_kernel       <<<K3G+K3B, 256, 0, stream>>>(gi, gv, be, bv, gcur_, gbuck, bcur_, bbuck);
  prep_kernel       <<<256,     256, 0, stream>>>(Wg, Wm, Wsg, Wg_pre, Wc_pre);
  gemm1_kernel      <<<G64,     256, 0, stream>>>(X, Wg_pre, xwb);
  gcn_gather2_kernel<<<NBIN,    256, 0, stream>>>(xwb, gbuck, gcoff, hiddenw);
  gemm2_kernel      <<<G64,     256, 0, stream>>>(hiddenw, Wc_pre, DSTw);
  edgebi2_kernel    <<<NBIN+EBLK, 256, 0, stream>>>(SRCw, DSTw, ed, nin, nout,
                                                    ein, eout, bbuck, bcoff, nnod, out);
}

// Round 15
// 422.292 us; speedup vs baseline: 1.5665x; 1.0577x over previous
//
#include <hip/hip_runtime.h>

typedef unsigned short u16t;
typedef unsigned int   u32t;
typedef unsigned long long u64t;

#define NNODE 100000
#define DIN   256
#define HIDN  128
#define DOUTN 64
#define NNZE  1600000
#define EDIR  500000
#define EBI   1000000
#define G64   1563           // ceil(NNODE/64)
#define NBIN  782            // ceil(NNODE/128), bin = key>>7
#define CH3   4096           // edges per partition block
#define K3G   391            // ceil(NNZE/CH3)
#define K3B   245            // ceil(EBI/CH3)
#define KPART (K3G+K3B)      // 636 partition blocks
#define CAPG  2432           // gcn entries per bin cap (mean 2048, sd 45 -> 8.5 sigma)
#define CAPB  1536           // bi entries per bin cap (mean 1280, sd 34 -> 7.5 sigma)
#define EBLK  15625          // EDIR/32: edge blocks (8 edges/wave, 4 waves)

typedef __attribute__((ext_vector_type(8))) short bf16x8;
typedef __attribute__((ext_vector_type(4))) float f32x4;
typedef __attribute__((ext_vector_type(4))) float f4v;

__device__ __forceinline__ u16t f2bf(float f){
  u32t u = __float_as_uint(f);
  u += 0x7FFFu + ((u>>16)&1u);          // round-to-nearest-even
  return (u16t)(u>>16);
}
__device__ __forceinline__ float2 up2(u32t w){
  return make_float2(__uint_as_float(w<<16), __uint_as_float(w&0xFFFF0000u));
}

// ---------------- union: coarse histogram (blocks [0,KPART)) + weight prep (after) ----------------
__global__ __launch_bounds__(256) void histprep_kernel(const int* __restrict__ gi,
                                                       const int* __restrict__ be,
                                                       u32t* __restrict__ gcnt_c,
                                                       u32t* __restrict__ bcnt_c,
                                                       const float* __restrict__ Wg,
                                                       const float* __restrict__ Wm,
                                                       const float* __restrict__ Wsg,
                                                       u16t* __restrict__ Wg_pre,
                                                       u16t* __restrict__ Wc_pre){
  __shared__ u32t h[1024];
  int blk = blockIdx.x, t = threadIdx.x;
  if(blk >= KPART){
    // ---- prep path ----
    int idx = (blk-KPART)*256 + t;              // 0..65535
    int e = idx & 7, l = (idx>>3) & 63, f = (idx>>9) & 63, sel = idx>>15;
    int k_in = ((e>>2)<<4) + ((l>>4)<<2) + (e&3);
    if(sel == 0){
      int ks = f>>3, nf = f&7;
      int k = ks*32 + k_in, n = nf*16 + (l&15);
      Wg_pre[idx] = f2bf(Wg[(size_t)k*HIDN + n]);
    } else {
      int ks = f>>4, nf = f&15;
      int k = ks*32 + k_in, c = nf*16 + (l&15);
      int half = c>>7, ci = c&127;
      const float* src = (ci&1) ? Wsg : Wm;
      Wc_pre[idx - 32768] = f2bf(src[(size_t)(half*128 + k)*DOUTN + (ci>>1)]);
    }
    return;
  }
  // ---- hist path ----
  const int* keys; u32t* outc; int E, e0;
  if(blk < K3G){ keys=gi; outc=gcnt_c; E=NNZE; e0=blk*CH3; }
  else         { keys=be; outc=bcnt_c; E=EBI;  e0=(blk-K3G)*CH3; }
  for(int i=t;i<1024;i+=256) h[i]=0;
  __syncthreads();
  for(int i=t;i<CH3;i+=256){
    int e=e0+i;
    if(e<E) atomicAdd(&h[(u32t)keys[e]>>7], 1u);
  }
  __syncthreads();
  for(int b=t;b<1024;b+=256){
    u32t c=h[b];
    if(c) atomicAdd(&outc[b], c);
  }
}

// ---------------- scan coarse counts -> offsets + cursors (2 blocks) ----------------
__global__ __launch_bounds__(256) void scan_coarse_kernel(u32t* __restrict__ gcnt_c,
                                                          u32t* __restrict__ gcoff,
                                                          u32t* __restrict__ gcur_,
                                                          u32t* __restrict__ bcnt_c,
                                                          u32t* __restrict__ bcoff,
                                                          u32t* __restrict__ bcur_){
  __shared__ u32t part[256];
  u32t *cnt, *coff, *cur;
  if(blockIdx.x==0){ cnt=gcnt_c; coff=gcoff; cur=gcur_; }
  else             { cnt=bcnt_c; coff=bcoff; cur=bcur_; }
  int t = threadIdx.x;
  u32t ch[4], s=0;
  #pragma unroll
  for(int j=0;j<4;j++){ int idx=t*4+j; ch[j] = (idx<NBIN)? cnt[idx] : 0u; s+=ch[j]; }
  part[t]=s; __syncthreads();
  for(int off=1;off<256;off<<=1){
    u32t x=(t>=off)?part[t-off]:0u;
    __syncthreads();
    part[t]+=x;
    __syncthreads();
  }
  u32t run=(t==0)?0u:part[t-1];
  #pragma unroll
  for(int j=0;j<4;j++){
    int idx=t*4+j;
    if(idx<NBIN){ coff[idx]=run; cur[idx]=run; run+=ch[j]; }
  }
  if(t==255) coff[NBIN]=part[255];
}

// ---------------- union: GEMM1 (blocks [0,G64)) + partition (blocks [G64,G64+KPART)) ----------------
// shared LDS union: gemm1 uses first 32KB as Xs; part carves 50176 B
__global__ __launch_bounds__(256) void partgemm1_kernel(const float* __restrict__ X,
                                                        const u16t* __restrict__ Wg_pre,
                                                        u16t* __restrict__ xwb,
                                                        const int* __restrict__ gi,
                                                        const float* __restrict__ gv,
                                                        const int* __restrict__ be,
                                                        const float* __restrict__ bv,
                                                        u32t* __restrict__ gcur_,
                                                        u64t* __restrict__ gbuck,
                                                        u32t* __restrict__ bcur_,
                                                        u64t* __restrict__ bbuck){
  __shared__ __align__(16) char smem[50176];
  const int t = threadIdx.x;
  if(blockIdx.x < G64){
    // ---------------- GEMM1 path ----------------
    u16t* Xs = (u16t*)smem;                     // 32 KB, 8B-granule XOR-swizzled
    const int l = t & 63, w = t >> 6;
    const int row0 = blockIdx.x * 64;
    for(int i=0;i<16;i++){
      int m = w*16 + i;
      int mg = min(row0 + m, NNODE-1);
      f4v f = __builtin_nontemporal_load((const f4v*)&X[(size_t)mg*DIN + l*4]);
      u32t lo = (u32t)f2bf(f[0]) | ((u32t)f2bf(f[1])<<16);
      u32t hi = (u32t)f2bf(f[2]) | ((u32t)f2bf(f[3])<<16);
      u32t* p = (u32t*)&Xs[m*256 + ((l ^ (m&15))<<2)];
      p[0] = lo; p[1] = hi;
    }
    __syncthreads();
    f32x4 acc[8];
    #pragma unroll
    for(int nf=0;nf<8;nf++) acc[nf] = (f32x4)(0.f);
    const int lm = l & 15, l4 = l >> 4;
    const int mrow = w*16 + lm;
    #pragma unroll 1
    for(int ks=0; ks<8; ks++){
      int kg = ks*8 + l4;
      union { uint2 u2[2]; bf16x8 v; } a;
      a.u2[0] = *(const uint2*)&Xs[mrow*256 + ((kg     ^ lm)<<2)];
      a.u2[1] = *(const uint2*)&Xs[mrow*256 + (((kg+4) ^ lm)<<2)];
      #pragma unroll
      for(int nf=0;nf<8;nf++){
        union { uint4 u4; bf16x8 v; } b;
        b.u4 = *(const uint4*)&Wg_pre[(size_t)((ks*8+nf)*64 + l)*8];
        acc[nf] = __builtin_amdgcn_mfma_f32_16x16x32_bf16(a.v, b.v, acc[nf], 0, 0, 0);
      }
    }
    #pragma unroll
    for(int r=0;r<4;r++){
      int gr = row0 + w*16 + l4*4 + r;
      if(gr < NNODE){
        #pragma unroll
        for(int nf=0;nf<8;nf++)
          xwb[(size_t)gr*HIDN + nf*16 + lm] = f2bf(acc[nf][r]);
      }
    }
    return;
  }
  // ---------------- partition path ----------------
  u32t* hist = (u32t*)smem;               // 1024 u32: counts -> cursor -> base
  u32t* scn  = (u32t*)(smem+4096);        // 1024 u32: local exclusive scan
  u32t* prt  = (u32t*)(smem+8192);        // 256 u32
  u64t* ebuf = (u64t*)(smem+9216);        // 4096 u64
  u16t* bins = (u16t*)(smem+41984);       // 4096 u16
  int blk = blockIdx.x - G64;
  const int *keys, *pay; const float* val; u32t* cursor; u64t* buck; int E, e0;
  if(blk < K3G){ keys=gi; pay=gi+NNZE; val=gv; cursor=gcur_; buck=gbuck; E=NNZE; e0=blk*CH3; }
  else         { keys=be; pay=be+EBI;  val=bv; cursor=bcur_; buck=bbuck; E=EBI;  e0=(blk-K3G)*CH3; }
  for(int i=t;i<1024;i+=256) hist[i]=0;
  __syncthreads();
  for(int i=t;i<CH3;i+=256){
    int e=e0+i;
    if(e<E) atomicAdd(&hist[(u32t)keys[e]>>7], 1u);
  }
  __syncthreads();
  // exclusive scan hist[1024] -> scn
  u32t ch[4], s=0;
  #pragma unroll
  for(int j=0;j<4;j++){ ch[j]=hist[t*4+j]; s+=ch[j]; }
  prt[t]=s; __syncthreads();
  for(int off=1;off<256;off<<=1){
    u32t x=(t>=off)?prt[t-off]:0u;
    __syncthreads();
    prt[t]+=x;
    __syncthreads();
  }
  u32t run=(t==0)?0u:prt[t-1];
  #pragma unroll
  for(int j=0;j<4;j++){ scn[t*4+j]=run; run+=ch[j]; }
  __syncthreads();
  for(int i=t;i<1024;i+=256) hist[i]=scn[i];   // hist becomes local cursor
  __syncthreads();
  // scatter into LDS, bin-grouped
  for(int i=t;i<CH3;i+=256){
    int e=e0+i;
    if(e<E){
      int k = keys[e];
      u32t b = (u32t)k>>7;
      u32t p = atomicAdd(&hist[b],1u);
      u64t ent = (u64t)((u32t)pay[e] | (((u32t)k&127u)<<20)) | ((u64t)__float_as_uint(val[e])<<32);
      ebuf[p]=ent; bins[p]=(u16t)b;
    }
  }
  __syncthreads();
  // reserve global space per bin; fold base into hist
  for(int b=t;b<1024;b+=256){
    u32t c = hist[b]-scn[b];
    u32t bs = c ? atomicAdd(&cursor[b], c) : 0u;
    hist[b] = bs;
  }
  __syncthreads();
  // coalesced write-out (consecutive i in a bin -> consecutive global addrs)
  int totalValid = prt[255];
  for(int i=t;i<totalValid;i+=256){
    u32t b = bins[i];
    buck[ (size_t)hist[b] + (u32t)i - scn[b] ] = ebuf[i];
  }
}

// ---------------- GCN gather: bin-per-block, in-LDS CSR + gather ----------------
__global__ __launch_bounds__(256) void gcn_gather2_kernel(const u16t* __restrict__ xwb,
                                                          const u64t* __restrict__ gbuck,
                                                          const u32t* __restrict__ gcoff,
                                                          u32t* __restrict__ hiddenw){
  __shared__ u64t ebuf[CAPG];
  __shared__ u32t hist[128], offs[129], cur[128], sc[128];
  int bin = blockIdx.x, t = threadIdx.x;
  u32t base = gcoff[bin], cnt = gcoff[bin+1] - base;
  if(t<128) hist[t]=0;
  __syncthreads();
  for(u32t i=t;i<cnt;i+=256)
    atomicAdd(&hist[(u32t)(gbuck[base+i]>>20)&127u], 1u);
  __syncthreads();
  if(t<128) sc[t]=hist[t];
  __syncthreads();
  for(int off=1;off<128;off<<=1){
    u32t x=(t>=off&&t<128)?sc[t-off]:0u;
    __syncthreads();
    if(t<128) sc[t]+=x;
    __syncthreads();
  }
  if(t<128){ offs[t+1]=sc[t]; cur[t]=sc[t]-hist[t]; if(t==0) offs[0]=0u; }
  __syncthreads();
  for(u32t i=t;i<cnt;i+=256){
    u64t e = gbuck[base+i];
    u32t p = atomicAdd(&cur[(u32t)(e>>20)&127u], 1u);
    ebuf[p]=e;
  }
  __syncthreads();
  int w=t>>6, l=t&63;
  const u32t* xww=(const u32t*)xwb;
  for(int idx=w; idx<128; idx+=4){
    int n = bin*128 + idx;
    if(n >= NNODE) continue;
    u32t s0=offs[idx], cnt2=offs[idx+1]-s0;
    float acc0=0.f, acc1=0.f;
    u32t nbr=(cnt2+3)&~3u;
    for(u32t j=0;j<nbr;j+=4){
      float2 xs[4]; float vs[4];
      #pragma unroll
      for(int q=0;q<4;q++){
        u32t jj=j+q;
        u64t e=(jj<cnt2)? ebuf[s0+jj] : 0ULL;
        vs[q]=__uint_as_float((u32t)(e>>32));
        xs[q]=up2(xww[(size_t)(e&0x1FFFFu)*64 + l]);
      }
      #pragma unroll
      for(int q=0;q<4;q++){ acc0+=vs[q]*xs[q].x; acc1+=vs[q]*xs[q].y; }
    }
    hiddenw[(size_t)n*64 + l] = (u32t)f2bf(acc0) | ((u32t)f2bf(acc1)<<16);
  }
}

// ---------------- GEMM2 (MFMA): SRCw (in-place over hiddenw) + DSTw ----------------
__global__ __launch_bounds__(256) void gemm2_kernel(u32t* __restrict__ hiddenw,
                                                    const u16t* __restrict__ Wc_pre,
                                                    u16t* __restrict__ DSTw){
  __shared__ __align__(16) u16t Hs[64*128];   // 16 KB
  const int t = threadIdx.x, l = t & 63, w = t >> 6;
  const int row0 = blockIdx.x * 64;
  for(int i=0;i<16;i++){
    int m = w*16 + i;
    int mg = min(row0 + m, NNODE-1);
    u32t v = hiddenw[(size_t)mg*64 + l];
    *(u32t*)&Hs[m*128 + (((l>>1) ^ (m&15))<<2) + ((l&1)<<1)] = v;
  }
  __syncthreads();
  f32x4 acc[16];
  #pragma unroll
  for(int nf=0;nf<16;nf++) acc[nf] = (f32x4)(0.f);
  const int lm = l & 15, l4 = l >> 4;
  const int mrow = w*16 + lm;
  #pragma unroll 1
  for(int ks=0; ks<4; ks++){
    int kg = ks*8 + l4;
    union { uint2 u2[2]; bf16x8 v; } a;
    a.u2[0] = *(const uint2*)&Hs[mrow*128 + ((kg     ^ lm)<<2)];
    a.u2[1] = *(const uint2*)&Hs[mrow*128 + (((kg+4) ^ lm)<<2)];
    #pragma unroll
    for(int nf=0;nf<16;nf++){
      union { uint4 u4; bf16x8 v; } b;
      b.u4 = *(const uint4*)&Wc_pre[(size_t)((ks*16+nf)*64 + l)*8];
      acc[nf] = __builtin_amdgcn_mfma_f32_16x16x32_bf16(a.v, b.v, acc[nf], 0, 0, 0);
    }
  }
  u16t* SRCw = (u16t*)hiddenw;   // in-place: this block's rows were staged above
  #pragma unroll
  for(int r=0;r<4;r++){
    int gr = row0 + w*16 + l4*4 + r;
    if(gr < NNODE){
      #pragma unroll
      for(int nf=0;nf<8;nf++)
        SRCw[(size_t)gr*HIDN + nf*16 + lm] = f2bf(acc[nf][r]);
      #pragma unroll
      for(int nf=8;nf<16;nf++)
        DSTw[(size_t)gr*HIDN + (nf-8)*16 + lm] = f2bf(acc[nf][r]);
    }
  }
}

// ---------------- union kernel: bi bins (blocks [0,NBIN)) + edge heads (8 edges/wave) ----------------
__global__ __launch_bounds__(256) void edgebi2_kernel(const u16t* __restrict__ SRCb,
                                                      const u16t* __restrict__ DSTb,
                                                      const int*  __restrict__ ed,
                                                      const float* __restrict__ nin,
                                                      const float* __restrict__ nout,
                                                      float* __restrict__ ein,
                                                      float* __restrict__ eout,
                                                      const u64t* __restrict__ bbuck,
                                                      const u32t* __restrict__ bcoff,
                                                      const float* __restrict__ nn,
                                                      float* __restrict__ outp){
  __shared__ u64t ebuf[CAPB];
  __shared__ u32t hist[128], offs[129], cur[128], sc[128];
  const int t = threadIdx.x;
  const u32t* Sw = (const u32t*)SRCb;
  const u32t* Dw = (const u32t*)DSTb;
  if(blockIdx.x >= NBIN){
    // ---------- edge path: 8 edges per wave ----------
    const int e0 = ((int)(blockIdx.x - NBIN)*4 + (t>>6))*8;
    const int l = t & 63;
    int s[8], d[8];
    #pragma unroll
    for(int q=0;q<8;q++){ s[q] = ed[e0+q]; d[q] = ed[EDIR+e0+q]; }
    float2 Ss[8], Ds[8], Sd[8], Dd[8];
    float ni[8], no[8];
    #pragma unroll
    for(int q=0;q<8;q++){
      Ss[q] = up2(Sw[(size_t)s[q]*64 + l]);
      Ds[q] = up2(Dw[(size_t)s[q]*64 + l]);
      Sd[q] = up2(Sw[(size_t)d[q]*64 + l]);
      Dd[q] = up2(Dw[(size_t)d[q]*64 + l]);
      ni[q] = __builtin_nontemporal_load(&nin[(size_t)(e0+q)*DOUTN + l]);
      no[q] = __builtin_nontemporal_load(&nout[(size_t)(e0+q)*DOUTN + l]);
    }
    #pragma unroll
    for(int q=0;q<8;q++){
      size_t o = (size_t)(e0+q)*DOUTN + l;
      float miu_in  = Ss[q].x + Dd[q].x, ls_in  = Ss[q].y + Dd[q].y;
      float miu_out = Sd[q].x + Ds[q].x, ls_out = Sd[q].y + Ds[q].y;
      __builtin_nontemporal_store(ni[q] * __expf(ls_in)  + miu_in,  &ein[o]);
      __builtin_nontemporal_store(no[q] * __expf(ls_out) + miu_out, &eout[o]);
    }
    return;
  }
  // ---------- bi path: bin-per-block in-LDS CSR + gather + finalize ----------
  int bin = blockIdx.x;
  u32t base = bcoff[bin], cnt = bcoff[bin+1] - base;
  if(t<128) hist[t]=0;
  __syncthreads();
  for(u32t i=t;i<cnt;i+=256)
    atomicAdd(&hist[(u32t)(bbuck[base+i]>>20)&127u], 1u);
  __syncthreads();
  if(t<128) sc[t]=hist[t];
  __syncthreads();
  for(int off=1;off<128;off<<=1){
    u32t x=(t>=off&&t<128)?sc[t-off]:0u;
    __syncthreads();
    if(t<128) sc[t]+=x;
    __syncthreads();
  }
  if(t<128){ offs[t+1]=sc[t]; cur[t]=sc[t]-hist[t]; if(t==0) offs[0]=0u; }
  __syncthreads();
  for(u32t i=t;i<cnt;i+=256){
    u64t e = bbuck[base+i];
    u32t p = atomicAdd(&cur[(u32t)(e>>20)&127u], 1u);
    ebuf[p]=e;
  }
  __syncthreads();
  int w=t>>6, l=t&63;
  for(int idx=w; idx<128; idx+=4){
    int n = bin*128 + idx;
    if(n >= NNODE) continue;
    float2 S = up2(Sw[(size_t)n*64 + l]);
    u32t s0=offs[idx], cnt2=offs[idx+1]-s0;
    float nmiu=0.f, nvar=0.f;
    u32t nbr=(cnt2+3)&~3u;
    for(u32t j=0;j<nbr;j+=4){
      float2 Dq[4]; float vs[4];
      #pragma unroll
      for(int q=0;q<4;q++){
        u32t jj=j+q;
        u64t e=(jj<cnt2)? ebuf[s0+jj] : 0ULL;
        vs[q]=__uint_as_float((u32t)(e>>32));
        Dq[q]=up2(Dw[(size_t)(e&0x1FFFFu)*64 + l]);
      }
      #pragma unroll
      for(int q=0;q<4;q++){
        nmiu += vs[q]*(S.x+Dq[q].x);
        nvar += vs[q]*vs[q]*__expf(S.y+Dq[q].y);
      }
    }
    size_t o = (size_t)n*DOUTN + l;
    float nd = __builtin_nontemporal_load(&nn[o]);
    __builtin_nontemporal_store(nd*sqrtf(nvar) + nmiu, &outp[o]);  // exp(0.5*log v)==sqrt(v)
  }
}

extern "C" void kernel_launch(void* const* d_in, const int* in_sizes, int n_in,
                              void* d_out, int out_size, void* d_ws, size_t ws_size,
                              hipStream_t stream){
  const float* X    = (const float*)d_in[0];
  const float* Wg   = (const float*)d_in[1];
  const float* Wm   = (const float*)d_in[2];
  const float* Wsg  = (const float*)d_in[3];
  const float* gv   = (const float*)d_in[4];
  const float* bv   = (const float*)d_in[5];
  const float* nin  = (const float*)d_in[6];
  const float* nout = (const float*)d_in[7];
  const float* nnod = (const float*)d_in[8];
  const int*  gi   = (const int*)d_in[9];
  const int*  ed   = (const int*)d_in[10];
  const int*  be   = (const int*)d_in[11];

  // workspace (76.8 MB):
  //  [0,12.8M)        gbuck u64            -> phase2: DSTw bf16 [0,25.6M)
  //  [12.8M,38.4M)    xwb bf16             -> (tail of DSTw)
  //  [38.4M,+24K)     coarse meta: gcnt_c|bcnt_c|gcoff|gcur_|bcoff|bcur_ (1024 u32 each)
  //  [40.0M,48.0M)    bbuck u64 (lives until edgebi2)
  //  [51.2M,76.8M)    hiddenw u32-packed bf16 -> in-place SRCw bf16 after gemm2
  char* ws = (char*)d_ws;
  u64t*  gbuck   = (u64t*)ws;
  u16t*  xwb     = (u16t*)(ws + 12800000);
  u32t*  gcnt_c  = (u32t*)(ws + 38400000);
  u32t*  bcnt_c  = (u32t*)(ws + 38404096);
  u32t*  gcoff   = (u32t*)(ws + 38408192);
  u32t*  gcur_   = (u32t*)(ws + 38412288);
  u32t*  bcoff   = (u32t*)(ws + 38416384);
  u32t*  bcur_   = (u32t*)(ws + 38420480);
  u64t*  bbuck   = (u64t*)(ws + 40003168);
  u32t*  hiddenw = (u32t*)(ws + 51200000);
  u16t*  SRCw    = (u16t*)hiddenw;
  u16t*  DSTw    = (u16t*)ws;

  float* out  = (float*)d_out;
  float* ein  = out + (size_t)NNODE*DOUTN;
  float* eout = ein + (size_t)EDIR*DOUTN;
  // weight-prep arrays in tail of d_out's node region; dead before edgebi2 overwrites
  u16t* Wg_pre = (u16t*)((char*)d_out + 25600000 - 131072);
  u16t* Wc_pre = Wg_pre + 32768;

  (void)hipMemsetAsync(gcnt_c, 0, 8192, stream);                // gcnt_c + bcnt_c
  histprep_kernel   <<<KPART+256, 256, 0, stream>>>(gi, be, gcnt_c, bcnt_c,
                                                    Wg, Wm, Wsg, Wg_pre, Wc_pre);
  scan_coarse_kernel<<<2,         256, 0, stream>>>(gcnt_c, gcoff, gcur_, bcnt_c, bcoff, bcur_);
  partgemm1_kernel  <<<G64+KPART, 256, 0, stream>>>(X, Wg_pre, xwb,
                                                    gi, gv, be, bv, gcur_, gbuck, bcur_, bbuck);
  gcn_gather2_kernel<<<NBIN,      256, 0, stream>>>(xwb, gbuck, gcoff, hiddenw);
  gemm2_kernel      <<<G64,       256, 0, stream>>>(hiddenw, Wc_pre, DSTw);
  edgebi2_kernel    <<<NBIN+EBLK, 256, 0, stream>>>(SRCw, DSTw, ed, nin, nout,
                                                    ein, eout, bbuck, bcoff, nnod, out);
}

// Round 16
// 383.844 us; speedup vs baseline: 1.7234x; 1.1002x over previous
//
#include <hip/hip_runtime.h>
#include <hip/hip_bf16.h>
#include <string.h>

typedef unsigned short u16t;
typedef unsigned int   u32t;
typedef unsigned long long u64t;

#define NNODE 100000
#define DIN   256
#define HIDN  128
#define DOUTN 64
#define NNZE  1600000
#define EDIR  500000
#define EBI   1000000
#define G64   1563           // ceil(NNODE/64)
#define NBIN  782            // ceil(NNODE/128), bin = key>>7
#define CH3   4096           // edges per partition block
#define K3G   391            // ceil(NNZE/CH3)
#define K3B   245            // ceil(EBI/CH3)
#define KPART (K3G+K3B)      // 636 partition blocks
#define CAPG  2432           // gcn entries per bin cap
#define CAPB  1536           // bi entries per bin cap
#define EBLK  15625          // EDIR/32: edge blocks (8 edges/wave, 4 waves)

typedef __attribute__((ext_vector_type(8))) short bf16x8;
typedef __attribute__((ext_vector_type(4))) float f32x4;
typedef __attribute__((ext_vector_type(4))) float f4v;

// packed f32x2 -> bf16x2 (RNE) — compiler emits v_cvt_pk_bf16_f32
__device__ __forceinline__ u32t pk2bf(float a, float b){
  __hip_bfloat162 h = __float22bfloat162_rn(make_float2(a, b));
  union { __hip_bfloat162 h2; u32t u; } c; c.h2 = h; return c.u;
}
__device__ __forceinline__ u16t s2bf(float a){
  __hip_bfloat16 h = __float2bfloat16(a);
  union { __hip_bfloat16 h1; u16t u; } c; c.h1 = h; return c.u;
}
__device__ __forceinline__ float2 up2(u32t w){
  return make_float2(__uint_as_float(w<<16), __uint_as_float(w&0xFFFF0000u));
}

// ---------------- union: coarse histogram (blocks [0,KPART)) + weight prep (after) ----------------
__global__ __launch_bounds__(256) void histprep_kernel(const int* __restrict__ gi,
                                                       const int* __restrict__ be,
                                                       u32t* __restrict__ gcnt_c,
                                                       u32t* __restrict__ bcnt_c,
                                                       const float* __restrict__ Wg,
                                                       const float* __restrict__ Wm,
                                                       const float* __restrict__ Wsg,
                                                       u16t* __restrict__ Wg_pre,
                                                       u16t* __restrict__ Wc_pre){
  __shared__ u32t h[1024];
  int blk = blockIdx.x, t = threadIdx.x;
  if(blk >= KPART){
    // ---- prep path ----
    int idx = (blk-KPART)*256 + t;              // 0..65535
    int e = idx & 7, l = (idx>>3) & 63, f = (idx>>9) & 63, sel = idx>>15;
    int k_in = ((e>>2)<<4) + ((l>>4)<<2) + (e&3);
    if(sel == 0){
      int ks = f>>3, nf = f&7;
      int k = ks*32 + k_in, n = nf*16 + (l&15);
      Wg_pre[idx] = s2bf(Wg[(size_t)k*HIDN + n]);
    } else {
      int ks = f>>4, nf = f&15;
      int k = ks*32 + k_in, c = nf*16 + (l&15);
      int half = c>>7, ci = c&127;
      const float* src = (ci&1) ? Wsg : Wm;
      Wc_pre[idx - 32768] = s2bf(src[(size_t)(half*128 + k)*DOUTN + (ci>>1)]);
    }
    return;
  }
  // ---- hist path ----
  const int* keys; u32t* outc; int E, e0;
  if(blk < K3G){ keys=gi; outc=gcnt_c; E=NNZE; e0=blk*CH3; }
  else         { keys=be; outc=bcnt_c; E=EBI;  e0=(blk-K3G)*CH3; }
  for(int i=t;i<1024;i+=256) h[i]=0;
  __syncthreads();
  for(int i=t;i<CH3;i+=256){
    int e=e0+i;
    if(e<E) atomicAdd(&h[(u32t)keys[e]>>7], 1u);
  }
  __syncthreads();
  for(int b=t;b<1024;b+=256){
    u32t c=h[b];
    if(c) atomicAdd(&outc[b], c);
  }
}

// ---------------- scan coarse counts -> offsets + cursors (2 blocks) ----------------
__global__ __launch_bounds__(256) void scan_coarse_kernel(u32t* __restrict__ gcnt_c,
                                                          u32t* __restrict__ gcoff,
                                                          u32t* __restrict__ gcur_,
                                                          u32t* __restrict__ bcnt_c,
                                                          u32t* __restrict__ bcoff,
                                                          u32t* __restrict__ bcur_){
  __shared__ u32t part[256];
  u32t *cnt, *coff, *cur;
  if(blockIdx.x==0){ cnt=gcnt_c; coff=gcoff; cur=gcur_; }
  else             { cnt=bcnt_c; coff=bcoff; cur=bcur_; }
  int t = threadIdx.x;
  u32t ch[4], s=0;
  #pragma unroll
  for(int j=0;j<4;j++){ int idx=t*4+j; ch[j] = (idx<NBIN)? cnt[idx] : 0u; s+=ch[j]; }
  part[t]=s; __syncthreads();
  for(int off=1;off<256;off<<=1){
    u32t x=(t>=off)?part[t-off]:0u;
    __syncthreads();
    part[t]+=x;
    __syncthreads();
  }
  u32t run=(t==0)?0u:part[t-1];
  #pragma unroll
  for(int j=0;j<4;j++){
    int idx=t*4+j;
    if(idx<NBIN){ coff[idx]=run; cur[idx]=run; run+=ch[j]; }
  }
  if(t==255) coff[NBIN]=part[255];
}

// ---------------- union: GEMM1 (blocks [0,G64)) + partition (blocks [G64,G64+KPART)) ----------------
__global__ __launch_bounds__(256) void partgemm1_kernel(const float* __restrict__ X,
                                                        const u16t* __restrict__ Wg_pre,
                                                        u16t* __restrict__ xwb,
                                                        const int* __restrict__ gi,
                                                        const float* __restrict__ gv,
                                                        const int* __restrict__ be,
                                                        const float* __restrict__ bv,
                                                        u32t* __restrict__ gcur_,
                                                        u64t* __restrict__ gbuck,
                                                        u32t* __restrict__ bcur_,
                                                        u64t* __restrict__ bbuck){
  __shared__ __align__(16) char smem[50176];
  const int t = threadIdx.x;
  if(blockIdx.x < G64){
    // ---------------- GEMM1 path ----------------
    u16t* Xs = (u16t*)smem;                     // 32 KB, 8B-granule XOR-swizzled
    const int l = t & 63, w = t >> 6;
    const int row0 = blockIdx.x * 64;
    for(int i=0;i<16;i++){
      int m = w*16 + i;
      int mg = min(row0 + m, NNODE-1);
      f4v f = __builtin_nontemporal_load((const f4v*)&X[(size_t)mg*DIN + l*4]);
      u32t* p = (u32t*)&Xs[m*256 + ((l ^ (m&15))<<2)];
      p[0] = pk2bf(f[0], f[1]);
      p[1] = pk2bf(f[2], f[3]);
    }
    __syncthreads();
    f32x4 acc[8];
    #pragma unroll
    for(int nf=0;nf<8;nf++) acc[nf] = (f32x4)(0.f);
    const int lm = l & 15, l4 = l >> 4;
    const int mrow = w*16 + lm;
    #pragma unroll 1
    for(int ks=0; ks<8; ks++){
      int kg = ks*8 + l4;
      union { uint2 u2[2]; bf16x8 v; } a;
      a.u2[0] = *(const uint2*)&Xs[mrow*256 + ((kg     ^ lm)<<2)];
      a.u2[1] = *(const uint2*)&Xs[mrow*256 + (((kg+4) ^ lm)<<2)];
      #pragma unroll
      for(int nf=0;nf<8;nf++){
        union { uint4 u4; bf16x8 v; } b;
        b.u4 = *(const uint4*)&Wg_pre[(size_t)((ks*8+nf)*64 + l)*8];
        acc[nf] = __builtin_amdgcn_mfma_f32_16x16x32_bf16(a.v, b.v, acc[nf], 0, 0, 0);
      }
    }
    #pragma unroll
    for(int r=0;r<4;r++){
      int gr = row0 + w*16 + l4*4 + r;
      if(gr < NNODE){
        #pragma unroll
        for(int nf=0;nf<8;nf++)
          xwb[(size_t)gr*HIDN + nf*16 + lm] = s2bf(acc[nf][r]);
      }
    }
    return;
  }
  // ---------------- partition path ----------------
  u32t* hist = (u32t*)smem;               // 1024 u32: counts -> cursor -> base
  u32t* scn  = (u32t*)(smem+4096);        // 1024 u32: local exclusive scan
  u32t* prt  = (u32t*)(smem+8192);        // 256 u32
  u64t* ebuf = (u64t*)(smem+9216);        // 4096 u64
  u16t* bins = (u16t*)(smem+41984);       // 4096 u16
  int blk = blockIdx.x - G64;
  const int *keys, *pay; const float* val; u32t* cursor; u64t* buck; int E, e0;
  if(blk < K3G){ keys=gi; pay=gi+NNZE; val=gv; cursor=gcur_; buck=gbuck; E=NNZE; e0=blk*CH3; }
  else         { keys=be; pay=be+EBI;  val=bv; cursor=bcur_; buck=bbuck; E=EBI;  e0=(blk-K3G)*CH3; }
  for(int i=t;i<1024;i+=256) hist[i]=0;
  __syncthreads();
  for(int i=t;i<CH3;i+=256){
    int e=e0+i;
    if(e<E) atomicAdd(&hist[(u32t)keys[e]>>7], 1u);
  }
  __syncthreads();
  u32t ch[4], s=0;
  #pragma unroll
  for(int j=0;j<4;j++){ ch[j]=hist[t*4+j]; s+=ch[j]; }
  prt[t]=s; __syncthreads();
  for(int off=1;off<256;off<<=1){
    u32t x=(t>=off)?prt[t-off]:0u;
    __syncthreads();
    prt[t]+=x;
    __syncthreads();
  }
  u32t run=(t==0)?0u:prt[t-1];
  #pragma unroll
  for(int j=0;j<4;j++){ scn[t*4+j]=run; run+=ch[j]; }
  __syncthreads();
  for(int i=t;i<1024;i+=256) hist[i]=scn[i];   // hist becomes local cursor
  __syncthreads();
  for(int i=t;i<CH3;i+=256){
    int e=e0+i;
    if(e<E){
      int k = keys[e];
      u32t b = (u32t)k>>7;
      u32t p = atomicAdd(&hist[b],1u);
      u64t ent = (u64t)((u32t)pay[e] | (((u32t)k&127u)<<20)) | ((u64t)__float_as_uint(val[e])<<32);
      ebuf[p]=ent; bins[p]=(u16t)b;
    }
  }
  __syncthreads();
  for(int b=t;b<1024;b+=256){
    u32t c = hist[b]-scn[b];
    u32t bs = c ? atomicAdd(&cursor[b], c) : 0u;
    hist[b] = bs;
  }
  __syncthreads();
  int totalValid = prt[255];
  for(int i=t;i<totalValid;i+=256){
    u32t b = bins[i];
    buck[ (size_t)hist[b] + (u32t)i - scn[b] ] = ebuf[i];
  }
}

// ---------------- GCN gather: bin-per-block, in-LDS CSR + gather (8x MLP) ----------------
__global__ __launch_bounds__(256) void gcn_gather2_kernel(const u16t* __restrict__ xwb,
                                                          const u64t* __restrict__ gbuck,
                                                          const u32t* __restrict__ gcoff,
                                                          u32t* __restrict__ hiddenw){
  __shared__ u64t ebuf[CAPG];
  __shared__ u32t hist[128], offs[129], cur[128], sc[128];
  int bin = blockIdx.x, t = threadIdx.x;
  u32t base = gcoff[bin], cnt = gcoff[bin+1] - base;
  if(t<128) hist[t]=0;
  __syncthreads();
  for(u32t i=t;i<cnt;i+=256)
    atomicAdd(&hist[(u32t)(gbuck[base+i]>>20)&127u], 1u);
  __syncthreads();
  if(t<128) sc[t]=hist[t];
  __syncthreads();
  for(int off=1;off<128;off<<=1){
    u32t x=(t>=off&&t<128)?sc[t-off]:0u;
    __syncthreads();
    if(t<128) sc[t]+=x;
    __syncthreads();
  }
  if(t<128){ offs[t+1]=sc[t]; cur[t]=sc[t]-hist[t]; if(t==0) offs[0]=0u; }
  __syncthreads();
  for(u32t i=t;i<cnt;i+=256){
    u64t e = gbuck[base+i];
    u32t p = atomicAdd(&cur[(u32t)(e>>20)&127u], 1u);
    ebuf[p]=e;
  }
  __syncthreads();
  int w=t>>6, l=t&63;
  const u32t* xww=(const u32t*)xwb;
  for(int idx=w; idx<128; idx+=4){
    int n = bin*128 + idx;
    if(n >= NNODE) continue;
    u32t s0=offs[idx], cnt2=offs[idx+1]-s0;
    float acc0=0.f, acc1=0.f;
    u32t nbr=(cnt2+7)&~7u;
    for(u32t j=0;j<nbr;j+=8){
      float2 xs[8]; float vs[8];
      #pragma unroll
      for(int q=0;q<8;q++){
        u32t jj=j+q;
        u64t e=(jj<cnt2)? ebuf[s0+jj] : 0ULL;   // pad: v=0, row 0 (L2-hot) — harmless
        vs[q]=__uint_as_float((u32t)(e>>32));
        xs[q]=up2(xww[(size_t)(e&0x1FFFFu)*64 + l]);
      }
      #pragma unroll
      for(int q=0;q<8;q++){ acc0+=vs[q]*xs[q].x; acc1+=vs[q]*xs[q].y; }
    }
    hiddenw[(size_t)n*64 + l] = pk2bf(acc0, acc1);
  }
}

// ---------------- GEMM2 (MFMA): SRCw (in-place over hiddenw) + DSTw ----------------
__global__ __launch_bounds__(256) void gemm2_kernel(u32t* __restrict__ hiddenw,
                                                    const u16t* __restrict__ Wc_pre,
                                                    u16t* __restrict__ DSTw){
  __shared__ __align__(16) u16t Hs[64*128];   // 16 KB
  const int t = threadIdx.x, l = t & 63, w = t >> 6;
  const int row0 = blockIdx.x * 64;
  for(int i=0;i<16;i++){
    int m = w*16 + i;
    int mg = min(row0 + m, NNODE-1);
    u32t v = hiddenw[(size_t)mg*64 + l];
    *(u32t*)&Hs[m*128 + (((l>>1) ^ (m&15))<<2) + ((l&1)<<1)] = v;
  }
  __syncthreads();
  f32x4 acc[16];
  #pragma unroll
  for(int nf=0;nf<16;nf++) acc[nf] = (f32x4)(0.f);
  const int lm = l & 15, l4 = l >> 4;
  const int mrow = w*16 + lm;
  #pragma unroll 1
  for(int ks=0; ks<4; ks++){
    int kg = ks*8 + l4;
    union { uint2 u2[2]; bf16x8 v; } a;
    a.u2[0] = *(const uint2*)&Hs[mrow*128 + ((kg     ^ lm)<<2)];
    a.u2[1] = *(const uint2*)&Hs[mrow*128 + (((kg+4) ^ lm)<<2)];
    #pragma unroll
    for(int nf=0;nf<16;nf++){
      union { uint4 u4; bf16x8 v; } b;
      b.u4 = *(const uint4*)&Wc_pre[(size_t)((ks*16+nf)*64 + l)*8];
      acc[nf] = __builtin_amdgcn_mfma_f32_16x16x32_bf16(a.v, b.v, acc[nf], 0, 0, 0);
    }
  }
  u16t* SRCw = (u16t*)hiddenw;   // in-place: this block's rows were staged above
  #pragma unroll
  for(int r=0;r<4;r++){
    int gr = row0 + w*16 + l4*4 + r;
    if(gr < NNODE){
      #pragma unroll
      for(int nf=0;nf<8;nf++)
        SRCw[(size_t)gr*HIDN + nf*16 + lm] = s2bf(acc[nf][r]);
      #pragma unroll
      for(int nf=8;nf<16;nf++)
        DSTw[(size_t)gr*HIDN + (nf-8)*16 + lm] = s2bf(acc[nf][r]);
    }
  }
}

// ---------------- union kernel: bi bins (blocks [0,NBIN)) + edge heads (8 edges/wave) ----------------
__global__ __launch_bounds__(256) void edgebi2_kernel(const u16t* __restrict__ SRCb,
                                                      const u16t* __restrict__ DSTb,
                                                      const int*  __restrict__ ed,
                                                      const float* __restrict__ nin,
                                                      const float* __restrict__ nout,
                                                      float* __restrict__ ein,
                                                      float* __restrict__ eout,
                                                      const u64t* __restrict__ bbuck,
                                                      const u32t* __restrict__ bcoff,
                                                      const float* __restrict__ nn,
                                                      float* __restrict__ outp){
  __shared__ u64t ebuf[CAPB];
  __shared__ u32t hist[128], offs[129], cur[128], sc[128];
  const int t = threadIdx.x;
  const u32t* Sw = (const u32t*)SRCb;
  const u32t* Dw = (const u32t*)DSTb;
  if(blockIdx.x >= NBIN){
    // ---------- edge path: 8 edges per wave ----------
    const int e0 = ((int)(blockIdx.x - NBIN)*4 + (t>>6))*8;
    const int l = t & 63;
    int s[8], d[8];
    #pragma unroll
    for(int q=0;q<8;q++){ s[q] = ed[e0+q]; d[q] = ed[EDIR+e0+q]; }
    float2 Ss[8], Ds[8], Sd[8], Dd[8];
    float ni[8], no[8];
    #pragma unroll
    for(int q=0;q<8;q++){
      Ss[q] = up2(Sw[(size_t)s[q]*64 + l]);
      Ds[q] = up2(Dw[(size_t)s[q]*64 + l]);
      Sd[q] = up2(Sw[(size_t)d[q]*64 + l]);
      Dd[q] = up2(Dw[(size_t)d[q]*64 + l]);
      ni[q] = __builtin_nontemporal_load(&nin[(size_t)(e0+q)*DOUTN + l]);
      no[q] = __builtin_nontemporal_load(&nout[(size_t)(e0+q)*DOUTN + l]);
    }
    #pragma unroll
    for(int q=0;q<8;q++){
      size_t o = (size_t)(e0+q)*DOUTN + l;
      float miu_in  = Ss[q].x + Dd[q].x, ls_in  = Ss[q].y + Dd[q].y;
      float miu_out = Sd[q].x + Ds[q].x, ls_out = Sd[q].y + Ds[q].y;
      __builtin_nontemporal_store(ni[q] * __expf(ls_in)  + miu_in,  &ein[o]);
      __builtin_nontemporal_store(no[q] * __expf(ls_out) + miu_out, &eout[o]);
    }
    return;
  }
  // ---------- bi path: bin-per-block in-LDS CSR + gather + finalize ----------
  int bin = blockIdx.x;
  u32t base = bcoff[bin], cnt = bcoff[bin+1] - base;
  if(t<128) hist[t]=0;
  __syncthreads();
  for(u32t i=t;i<cnt;i+=256)
    atomicAdd(&hist[(u32t)(bbuck[base+i]>>20)&127u], 1u);
  __syncthreads();
  if(t<128) sc[t]=hist[t];
  __syncthreads();
  for(int off=1;off<128;off<<=1){
    u32t x=(t>=off&&t<128)?sc[t-off]:0u;
    __syncthreads();
    if(t<128) sc[t]+=x;
    __syncthreads();
  }
  if(t<128){ offs[t+1]=sc[t]; cur[t]=sc[t]-hist[t]; if(t==0) offs[0]=0u; }
  __syncthreads();
  for(u32t i=t;i<cnt;i+=256){
    u64t e = bbuck[base+i];
    u32t p = atomicAdd(&cur[(u32t)(e>>20)&127u], 1u);
    ebuf[p]=e;
  }
  __syncthreads();
  int w=t>>6, l=t&63;
  for(int idx=w; idx<128; idx+=4){
    int n = bin*128 + idx;
    if(n >= NNODE) continue;
    float2 S = up2(Sw[(size_t)n*64 + l]);
    u32t s0=offs[idx], cnt2=offs[idx+1]-s0;
    float nmiu=0.f, nvar=0.f;
    u32t nbr=(cnt2+3)&~3u;
    for(u32t j=0;j<nbr;j+=4){
      float2 Dq[4]; float vs[4];
      #pragma unroll
      for(int q=0;q<4;q++){
        u32t jj=j+q;
        u64t e=(jj<cnt2)? ebuf[s0+jj] : 0ULL;
        vs[q]=__uint_as_float((u32t)(e>>32));
        Dq[q]=up2(Dw[(size_t)(e&0x1FFFFu)*64 + l]);
      }
      #pragma unroll
      for(int q=0;q<4;q++){
        nmiu += vs[q]*(S.x+Dq[q].x);
        nvar += vs[q]*vs[q]*__expf(S.y+Dq[q].y);
      }
    }
    size_t o = (size_t)n*DOUTN + l;
    float nd = __builtin_nontemporal_load(&nn[o]);
    __builtin_nontemporal_store(nd*sqrtf(nvar) + nmiu, &outp[o]);  // exp(0.5*log v)==sqrt(v)
  }
}

extern "C" void kernel_launch(void* const* d_in, const int* in_sizes, int n_in,
                              void* d_out, int out_size, void* d_ws, size_t ws_size,
                              hipStream_t stream){
  const float* X    = (const float*)d_in[0];
  const float* Wg   = (const float*)d_in[1];
  const float* Wm   = (const float*)d_in[2];
  const float* Wsg  = (const float*)d_in[3];
  const float* gv   = (const float*)d_in[4];
  const float* bv   = (const float*)d_in[5];
  const float* nin  = (const float*)d_in[6];
  const float* nout = (const float*)d_in[7];
  const float* nnod = (const float*)d_in[8];
  const int*  gi   = (const int*)d_in[9];
  const int*  ed   = (const int*)d_in[10];
  const int*  be   = (const int*)d_in[11];

  // workspace (76.8 MB):
  //  [0,12.8M)        gbuck u64            -> phase2: DSTw bf16 [0,25.6M)
  //  [12.8M,38.4M)    xwb bf16             -> (tail of DSTw)
  //  [38.4M,+24K)     coarse meta: gcnt_c|bcnt_c|gcoff|gcur_|bcoff|bcur_ (1024 u32 each)
  //  [40.0M,48.0M)    bbuck u64 (lives until edgebi2)
  //  [51.2M,76.8M)    hiddenw u32-packed bf16 -> in-place SRCw bf16 after gemm2
  char* ws = (char*)d_ws;
  u64t*  gbuck   = (u64t*)ws;
  u16t*  xwb     = (u16t*)(ws + 12800000);
  u32t*  gcnt_c  = (u32t*)(ws + 38400000);
  u32t*  bcnt_c  = (u32t*)(ws + 38404096);
  u32t*  gcoff   = (u32t*)(ws + 38408192);
  u32t*  gcur_   = (u32t*)(ws + 38412288);
  u32t*  bcoff   = (u32t*)(ws + 38416384);
  u32t*  bcur_   = (u32t*)(ws + 38420480);
  u64t*  bbuck   = (u64t*)(ws + 40003168);
  u32t*  hiddenw = (u32t*)(ws + 51200000);
  u16t*  SRCw    = (u16t*)hiddenw;
  u16t*  DSTw    = (u16t*)ws;

  float* out  = (float*)d_out;
  float* ein  = out + (size_t)NNODE*DOUTN;
  float* eout = ein + (size_t)EDIR*DOUTN;
  // weight-prep arrays in tail of d_out's node region; dead before edgebi2 overwrites
  u16t* Wg_pre = (u16t*)((char*)d_out + 25600000 - 131072);
  u16t* Wc_pre = Wg_pre + 32768;

  (void)hipMemsetAsync(gcnt_c, 0, 8192, stream);                // gcnt_c + bcnt_c
  histprep_kernel   <<<KPART+256, 256, 0, stream>>>(gi, be, gcnt_c, bcnt_c,
                                                    Wg, Wm, Wsg, Wg_pre, Wc_pre);
  scan_coarse_kernel<<<2,         256, 0, stream>>>(gcnt_c, gcoff, gcur_, bcnt_c, bcoff, bcur_);
  partgemm1_kernel  <<<G64+KPART, 256, 0, stream>>>(X, Wg_pre, xwb,
                                                    gi, gv, be, bv, gcur_, gbuck, bcur_, bbuck);
  gcn_gather2_kernel<<<NBIN,      256, 0, stream>>>(xwb, gbuck, gcoff, hiddenw);
  gemm2_kernel      <<<G64,       256, 0, stream>>>(hiddenw, Wc_pre, DSTw);
  edgebi2_kernel    <<<NBIN+EBLK, 256, 0, stream>>>(SRCw, DSTw, ed, nin, nout,
                                                    ein, eout, bbuck, bcoff, nnod, out);
}